// Round 10
// baseline (256.635 us; speedup 1.0000x reference)
//
#include <hip/hip_runtime.h>
#include <math.h>

#define NB   2048
#define DE   256
#define MEMN 16384
#define CAND_CAP 256
#define FSPL 32
#define FKPS 512
#define FIT  16   // 16 iters x 32 K-rows

typedef __attribute__((ext_vector_type(8)))  short  short8;
typedef __attribute__((ext_vector_type(16))) float  float16;
typedef __attribute__((ext_vector_type(4)))  unsigned uint4v;
typedef __attribute__((ext_vector_type(2)))  unsigned uint2v;

// ---------------- workspace layout (float element offsets), ~51.6 MB (verified fit, round 3) ----------------
static const size_t OFF_QB   = 0;          // 2048*256 bf16
static const size_t OFF_KB   = 262144;     // 16384*256 bf16
static const size_t OFF_VTB  = 2359296;    // Vt tiled [512][256][32] bf16
static const size_t OFF_LP   = 4456448;    // 32*2048 floats
static const size_t OFF_OPB  = 4521984;    // 32*2048*256 bf16
// stats overlay (dead before flash writes Opb), relative to OFF_OPB:
static const size_t SO_A    = 0;
static const size_t SO_X    = 65536;
static const size_t SO_MUP  = 131072;
static const size_t SO_DIST = 147456;

__device__ inline unsigned short f2bf(float f) {
  unsigned u = __float_as_uint(f);
  unsigned r = (u + 0x7fffu + ((u >> 16) & 1u)) >> 16;
  return (unsigned short)r;
}
__device__ inline float bf2f(unsigned short s) {
  return __uint_as_float((unsigned)s << 16);
}

// pack two f32 -> one u32 of 2x bf16 (RNE, lo in [15:0]) — bit-identical to f2bf pairs
__device__ inline unsigned cvtpk_bf16(float lo, float hi) {
  unsigned r;
  asm("v_cvt_pk_bf16_f32 %0, %1, %2" : "=v"(r) : "v"(lo), "v"(hi));
  return r;
}
// pack 8 f32 (two float4) into a short8 of bf16 via 4 cvt_pk ops
__device__ inline short8 pack8_bf16(float4 f0, float4 f1) {
  uint4v u = {cvtpk_bf16(f0.x, f0.y), cvtpk_bf16(f0.z, f0.w),
              cvtpk_bf16(f1.x, f1.y), cvtpk_bf16(f1.z, f1.w)};
  return __builtin_bit_cast(short8, u);
}

// exchange lane-halves between a lower-k word and a higher-k word (T12).
__device__ inline void halfswap(unsigned& lo, unsigned& hi, int h) {
#if __has_builtin(__builtin_amdgcn_permlane32_swap)
  (void)h;
  uint2v r = __builtin_amdgcn_permlane32_swap(lo, hi, false, false);
  lo = r.x; hi = r.y;
#else
  unsigned a = (unsigned)__shfl_xor((int)lo, 32, 64);
  unsigned b = (unsigned)__shfl_xor((int)hi, 32, 64);
  unsigned nlo = (h == 0) ? lo : b;
  unsigned nhi = (h == 0) ? a  : hi;
  lo = nlo; hi = nhi;
#endif
}

__device__ inline void bitonic_sort_u64(unsigned long long* key, int n, int tid, int nth) {
  for (int k = 2; k <= n; k <<= 1) {
    for (int j = k >> 1; j > 0; j >>= 1) {
      __syncthreads();
      for (int i = tid; i < n; i += nth) {
        int ixj = i ^ j;
        if (ixj > i) {
          unsigned long long a = key[i], b = key[ixj];
          bool up = ((i & k) == 0);
          if ((a > b) == up) { key[i] = b; key[ixj] = a; }
        }
      }
    }
  }
  __syncthreads();
}

// ---------------- mean partials (also zeroes A for covpart's atomics) ----------------
__global__ __launch_bounds__(256) void mupart_kernel(const float* __restrict__ z,
                                                     float* __restrict__ mup,
                                                     float* __restrict__ Az) {
  int d = threadIdx.x;
  int r0 = blockIdx.x * 32;
  float4 zero4 = {0.f, 0.f, 0.f, 0.f};
  *(float4*)&Az[(size_t)blockIdx.x * 1024 + threadIdx.x * 4] = zero4;
  float s = 0.f;
  for (int r = 0; r < 32; ++r) s += z[(size_t)(r0 + r) * DE + d];
  mup[blockIdx.x * DE + d] = s;
}

// ---------------- raw second-moment partials: Z^T Z over 128-row slice, atomicAdd into A ----------------
__global__ __launch_bounds__(256) void covpart_kernel(const float* __restrict__ z,
                                                      float* __restrict__ A) {
  __shared__ float As[16][68];
  __shared__ float Bs[16][68];
  int tid = threadIdx.x, tx = tid & 15, ty = tid >> 4;
  int i0 = blockIdx.x * 64, j0 = blockIdx.y * 64;
  int nbase = blockIdx.z * 128;
  float acc[4][4] = {};
  for (int nt = 0; nt < 8; ++nt) {
    int n0 = nbase + nt * 16;
    for (int e = tid; e < 1024; e += 256) {
      int c = e & 63, nn = e >> 6;
      As[nn][c] = z[(size_t)(n0 + nn) * DE + i0 + c];
      Bs[nn][c] = z[(size_t)(n0 + nn) * DE + j0 + c];
    }
    __syncthreads();
#pragma unroll
    for (int nn = 0; nn < 16; ++nn) {
      float4 a4 = *(const float4*)&As[nn][ty * 4];
      float4 b4 = *(const float4*)&Bs[nn][tx * 4];
      acc[0][0] += a4.x*b4.x; acc[0][1] += a4.x*b4.y; acc[0][2] += a4.x*b4.z; acc[0][3] += a4.x*b4.w;
      acc[1][0] += a4.y*b4.x; acc[1][1] += a4.y*b4.y; acc[1][2] += a4.y*b4.z; acc[1][3] += a4.y*b4.w;
      acc[2][0] += a4.z*b4.x; acc[2][1] += a4.z*b4.y; acc[2][2] += a4.z*b4.z; acc[2][3] += a4.z*b4.w;
      acc[3][0] += a4.w*b4.x; acc[3][1] += a4.w*b4.y; acc[3][2] += a4.w*b4.z; acc[3][3] += a4.w*b4.w;
    }
    __syncthreads();
  }
  for (int r = 0; r < 4; ++r) {
    int i = i0 + ty * 4 + r;
    for (int c = 0; c < 4; ++c) {
      int j = j0 + tx * 4 + c;
      atomicAdd(&A[(size_t)i * DE + j], acc[r][c]);
    }
  }
}

// ---------------- X = I + E + E^2 (E = I - A), E built on-the-fly ----------------
__global__ __launch_bounds__(256) void gemmx_kernel(const float* __restrict__ ZtZ,
                                                    const float* __restrict__ rcov,
                                                    const float* __restrict__ mup,
                                                    float* __restrict__ X) {
  __shared__ float Ea[16][17];
  __shared__ float Eb[16][17];
  __shared__ float mus[256];
  int t = threadIdx.x, tx = t & 15, ty = t >> 4;
  int i0 = blockIdx.x * 16, j0 = blockIdx.y * 16;
  {
    float s = 0.f;
    for (int b = 0; b < 64; ++b) s += mup[b * DE + t];
    mus[t] = s;   // raw column sums of z
  }
  __syncthreads();
  const float c1 = 0.01f / (float)(NB - 1);
  const float invN = 1.0f / (float)NB;
  float acc = 0.f;
  for (int k0 = 0; k0 < 256; k0 += 16) {
    int c = k0 + tx;
    {
      int r = i0 + ty;
      float base = 0.99f * rcov[(size_t)r * DE + c] +
                   c1 * (ZtZ[(size_t)r * DE + c] - mus[r] * mus[c] * invN);
      float e = -base;
      if (r == c) e += 1.0f - 1e-6f;
      Ea[ty][tx] = e;
    }
    {
      int r = j0 + ty;
      float base = 0.99f * rcov[(size_t)r * DE + c] +
                   c1 * (ZtZ[(size_t)r * DE + c] - mus[r] * mus[c] * invN);
      float e = -base;
      if (r == c) e += 1.0f - 1e-6f;
      Eb[ty][tx] = e;
    }
    __syncthreads();
#pragma unroll
    for (int k = 0; k < 16; ++k) acc += Ea[ty][k] * Eb[tx][k];   // E symmetric
    __syncthreads();
  }
  int r = i0 + ty, c = j0 + tx;
  float base = 0.99f * rcov[(size_t)r * DE + c] +
               c1 * (ZtZ[(size_t)r * DE + c] - mus[r] * mus[c] * invN);
  float e = -base;
  if (r == c) e += 1.0f - 1e-6f;
  X[(size_t)r * DE + c] = acc + e + ((r == c) ? 1.0f : 0.0f);
}

// dist: 4 rows per block, grid 512; rm = 0.99*rmean + 0.01*(sum mup)/N
__global__ __launch_bounds__(256) void dist_kernel(const float* __restrict__ z,
                                                   const float* __restrict__ rmean,
                                                   const float* __restrict__ mup,
                                                   const float* __restrict__ X,
                                                   float* __restrict__ dist) {
  __shared__ float cc[4][256];
  __shared__ float4 red[256];
  int n0 = blockIdx.x * 4, i = threadIdx.x;
  float s = 0.f;
  for (int b = 0; b < 64; ++b) s += mup[b * DE + i];
  float rmi = 0.99f * rmean[i] + 0.01f * s * (1.0f / (float)NB);
#pragma unroll
  for (int r = 0; r < 4; ++r) cc[r][i] = z[(size_t)(n0 + r) * DE + i] - rmi;
  __syncthreads();
  float y0 = 0.f, y1 = 0.f, y2 = 0.f, y3 = 0.f;
#pragma unroll 8
  for (int j = 0; j < DE; ++j) {
    float x = X[(size_t)j * DE + i];
    y0 += x * cc[0][j]; y1 += x * cc[1][j]; y2 += x * cc[2][j]; y3 += x * cc[3][j];
  }
  float4 v;
  v.x = y0 * cc[0][i]; v.y = y1 * cc[1][i]; v.z = y2 * cc[2][i]; v.w = y3 * cc[3][i];
  red[i] = v;
  __syncthreads();
  for (int sH = 128; sH > 0; sH >>= 1) {
    if (i < sH) {
      float4 a = red[i], b = red[i + sH];
      a.x += b.x; a.y += b.y; a.z += b.z; a.w += b.w;
      red[i] = a;
    }
    __syncthreads();
  }
  if (i < 4) {
    float4 tt = red[0];
    float d = (i == 0) ? tt.x : (i == 1) ? tt.y : (i == 2) ? tt.z : tt.w;
    dist[n0 + i] = sqrtf(fmaxf(d, 1e-8f));
  }
}

// ---------------- fused update: wave reductions, small-C wave sort, two-level extraction ----------------
// Round-10: expected C ~ 6 (kl ~ 2e-4, weights U[0,1]): the 36-barrier bitonic over
// 256 fixed slots was pure overhead. C<=64 path: single-wave rank sort (shfl loop,
// zero barriers). Bitonic kept as the C>64 fallback for correctness on any input.
__global__ __launch_bounds__(1024) void update_kernel(const float* __restrict__ dist,
                                                      const int* __restrict__ labels,
                                                      const float* __restrict__ weights,
                                                      const float* __restrict__ z,
                                                      float* __restrict__ memory) {
  __shared__ unsigned long long ikeys[NB];
  __shared__ unsigned long long ck[CAND_CAP];
  __shared__ unsigned long long gmin[16];
  __shared__ int slots[CAND_CAP], srcs[CAND_CAP];
  __shared__ float smin[16], smax[16];
  __shared__ int scnt[16];
  __shared__ float s_kl, s_dmin, s_inv;
  __shared__ int s_ccnt, s_m, s_stop, s_bg;
  int t = threadIdx.x;
  int wid = t >> 6, lane = t & 63;

  float mn = 1e30f, mx = -1e30f; int c1 = 0;
  for (int n = t; n < NB; n += 1024) {
    float d = dist[n];
    mn = fminf(mn, d); mx = fmaxf(mx, d);
    c1 += labels[n];
  }
#pragma unroll
  for (int o = 32; o > 0; o >>= 1) {
    mn = fminf(mn, __shfl_xor(mn, o, 64));
    mx = fmaxf(mx, __shfl_xor(mx, o, 64));
    c1 += __shfl_xor(c1, o, 64);
  }
  if (lane == 0) { smin[wid] = mn; smax[wid] = mx; scnt[wid] = c1; }
  if (t == 0) { s_ccnt = 0; s_m = 0; s_stop = 0; }
  __syncthreads();
  if (t == 0) {
    float a = 1e30f, b = -1e30f; int cc = 0;
    for (int i = 0; i < 16; ++i) { a = fminf(a, smin[i]); b = fmaxf(b, smax[i]); cc += scnt[i]; }
    float p1 = (float)cc / (float)NB;
    float p0 = (float)(NB - cc) / (float)NB;
    float kl = p0 * logf(fmaxf(2.f * p0, 1e-8f)) + p1 * logf(fmaxf(2.f * p1, 1e-8f));
    s_kl = fmaxf(kl, 0.f);
    s_dmin = a;
    s_inv = 1.0f / (b - a + 1e-8f);
  }
  __syncthreads();
  float kl = s_kl;

  for (int n = t; n < NB; n += 1024) {
    float imp = (1.0f + (dist[n] - s_dmin) * s_inv) * kl;
    ikeys[n] = ((unsigned long long)(unsigned)(~__float_as_uint(imp)) << 32) | (unsigned)n;
  }
  float thresh = 2.f * kl;
  for (int j = t; j < MEMN; j += 1024) {
    float wv = weights[j];
    if (wv < thresh) {
      int p = atomicAdd(&s_ccnt, 1);
      if (p < CAND_CAP) ck[p] = ((unsigned long long)__float_as_uint(wv) << 32) | (unsigned)j;
    }
  }
  __syncthreads();
  int C = s_ccnt; if (C > CAND_CAP) C = CAND_CAP;
  for (int i = t; i < CAND_CAP; i += 1024)
    if (i >= C) ck[i] = 0xFFFFFFFFFFFFFFFFULL;
  __syncthreads();
  if (C <= 64) {
    // single-wave rank sort, no barriers inside (wave 0 only)
    if (wid == 0) {
      unsigned long long key = (lane < C) ? ck[lane] : 0xFFFFFFFFFFFFFFFFULL;
      int rank = 0;
      for (int j = 0; j < 64; ++j) {
        unsigned long long o = (unsigned long long)__shfl((long long)key, j, 64);
        rank += (o < key) || (o == key && j < lane);
      }
      if (lane < C) ck[rank] = key;
    }
    __syncthreads();
  } else {
    bitonic_sort_u64(ck, CAND_CAP, t, 1024);
  }

  // group minima: wave wid owns ikeys[wid*128 .. wid*128+127]
  {
    unsigned long long a = ikeys[wid * 128 + lane];
    unsigned long long b = ikeys[wid * 128 + 64 + lane];
    unsigned long long mm = a < b ? a : b;
#pragma unroll
    for (int o = 32; o > 0; o >>= 1) {
      unsigned long long ot = (unsigned long long)__shfl_xor((long long)mm, o, 64);
      if (ot < mm) mm = ot;
    }
    if (lane == 0) gmin[wid] = mm;
  }
  __syncthreads();

  float prevv = 0.f;   // thread 0 only
  for (int i = 0; i < C; ++i) {
    if (t == 0) {
      unsigned long long best = 0xFFFFFFFFFFFFFFFFULL;
      for (int g = 0; g < 16; ++g) if (gmin[g] < best) best = gmin[g];
      float im = __uint_as_float(~(unsigned)(best >> 32));
      float wv = __uint_as_float((unsigned)(ck[i] >> 32));
      bool ok = (im > wv) && (i == 0 || prevv >= wv);
      if (ok) {
        int idx = (int)(best & 0xffffffffULL);
        slots[s_m] = (int)(ck[i] & 0xffffffffULL);
        srcs[s_m]  = idx;
        s_m++;
        prevv = im;
        ikeys[idx] = 0xFFFFFFFFFFFFFFFFULL;
        s_bg = idx >> 7;
      } else {
        s_stop = 1; s_bg = -1;
      }
    }
    __syncthreads();
    if (s_stop) break;
    if (wid == s_bg) {
      unsigned long long a = ikeys[wid * 128 + lane];
      unsigned long long b = ikeys[wid * 128 + 64 + lane];
      unsigned long long mm = a < b ? a : b;
#pragma unroll
      for (int o = 32; o > 0; o >>= 1) {
        unsigned long long ot = (unsigned long long)__shfl_xor((long long)mm, o, 64);
        if (ot < mm) mm = ot;
      }
      if (lane == 0) gmin[wid] = mm;
    }
    __syncthreads();
  }
  int m = s_m;
  for (int e = t; e < m * DE; e += 1024) {
    int i = e >> 8, d = e & 255;
    memory[(size_t)slots[i] * DE + d] = z[(size_t)srcs[i] * DE + d];
  }
}

// ---------------- fused Q/K/V projection GEMMs (one launch, role by flat block id) ----------------
// Round-10: bf16 packing via v_cvt_pk_bf16_f32 (2 elems/op, RNE, bit-identical to
// the old f2bf pairs) — cuts the VALU-heavy staging phase ~4x.
__global__ __launch_bounds__(256, 1) void qkv_kernel(
    const float* __restrict__ z, const float* __restrict__ memory,
    const float* __restrict__ Wq, const float* __restrict__ bq,
    const float* __restrict__ Wk, const float* __restrict__ bk,
    const float* __restrict__ Wv, const float* __restrict__ bv,
    unsigned short* __restrict__ Qbf, unsigned short* __restrict__ Kbf,
    unsigned short* __restrict__ Vtb) {
  __shared__ unsigned short Bsh[64 * 264];
  int flat = blockIdx.x;
  const float *Af, *Bf, *bias;
  unsigned short* C;
  int bias_row, vtile, gx, gy, ldC;
  if (flat < 64) {                 // Q = z@Wq^T+bq
    gx = flat & 15; gy = flat >> 4;
    Af = z; Bf = Wq; bias = bq; bias_row = 0; vtile = 0; C = Qbf; ldC = DE;
  } else if (flat < 576) {         // K = mem@Wk^T+bk
    int f = flat - 64; gx = f & 127; gy = f >> 7;
    Af = memory; Bf = Wk; bias = bk; bias_row = 0; vtile = 0; C = Kbf; ldC = DE;
  } else {                         // Vt = Wv@mem^T+bv, tiled output
    int f = flat - 576; gx = f & 1; gy = f >> 1;
    Af = Wv; Bf = memory; bias = bv; bias_row = 1; vtile = 1; C = Vtb; ldC = 0;
  }

  int tid = threadIdx.x;
  int w = tid >> 6, lane = tid & 63;
  int m = lane & 31, h = lane >> 5;
  int arow = gx * 128 + w * 32 + m;
  int n0 = gy * 64;

  short8 af[16];
#pragma unroll
  for (int kc = 0; kc < 16; ++kc) {
    const float* src = &Af[(size_t)arow * DE + kc * 16 + h * 8];
    float4 f0 = *(const float4*)&src[0];
    float4 f1 = *(const float4*)&src[4];
    af[kc] = pack8_bf16(f0, f1);
  }
  {
    int r = tid >> 2, q = tid & 3;
    const float* src = &Bf[(size_t)(n0 + r) * DE + q * 64];
    unsigned short* dst = &Bsh[r * 264 + q * 64];
#pragma unroll
    for (int j = 0; j < 8; ++j) {
      float4 f0 = *(const float4*)&src[j * 8];
      float4 f1 = *(const float4*)&src[j * 8 + 4];
      *(short8*)&dst[j * 8] = pack8_bf16(f0, f1);
    }
  }
  __syncthreads();

  float16 a0 = {}, a1 = {};
#pragma unroll
  for (int kc = 0; kc < 16; ++kc) {
    short8 b0 = *(const short8*)&Bsh[(0 * 32 + m) * 264 + kc * 16 + h * 8];
    short8 b1 = *(const short8*)&Bsh[(1 * 32 + m) * 264 + kc * 16 + h * 8];
    a0 = __builtin_amdgcn_mfma_f32_32x32x16_bf16(af[kc], b0, a0, 0, 0, 0);
    a1 = __builtin_amdgcn_mfma_f32_32x32x16_bf16(af[kc], b1, a1, 0, 0, 0);
  }
#pragma unroll
  for (int r = 0; r < 16; ++r) {
    int rr = (r & 3) + 8 * (r >> 2) + 4 * h;
    int orow = gx * 128 + w * 32 + rr;
    int oc0 = n0 + m, oc1 = n0 + 32 + m;
    float bb0 = bias_row ? bias[orow] : bias[oc0];
    float bb1 = bias_row ? bias[orow] : bias[oc1];
    if (!vtile) {
      C[(size_t)orow * ldC + oc0] = f2bf(a0[r] + bb0);
      C[(size_t)orow * ldC + oc1] = f2bf(a1[r] + bb1);
    } else {
      C[(size_t)(oc0 >> 5) * 8192 + (size_t)orow * 32 + (oc0 & 31)] = f2bf(a0[r] + bb0);
      C[(size_t)(oc1 >> 5) * 8192 + (size_t)orow * 32 + (oc1 & 31)] = f2bf(a1[r] + bb1);
    }
  }
}

// ---------------- MFMA flash attention: dh-merged, swizzled Ks, T12 in-reg softmax ----------------
// Round-10: the 264-pad Ks layout still 4-way bank-conflicts on QK reads
// (bank = (m*132 + C/4)%32, gcd 4). T2 XOR-swizzle on unpadded [32][256]:
// el = row*256 + (col8 ^ ((row&7)<<3)). Read groups of 4 lanes now hit the SAME
// 16B address (broadcast, conflict-free); stores stay <=2-way (free). Bit-identical.
// LDS: Ks 16384 + Vs 20480 = 36864 B.
__global__ __launch_bounds__(512, 2) void flash_kernel(
    const unsigned short* __restrict__ Qb, const unsigned short* __restrict__ Kb,
    const unsigned short* __restrict__ Vtb, unsigned short* __restrict__ Opb,
    float* __restrict__ Lp) {
  __shared__ unsigned short Ks[32 * 256];
  __shared__ unsigned short Vs[256 * 40];

  int tid = threadIdx.x;
  int w = tid >> 6, lane = tid & 63;
  int m = lane & 31, h = lane >> 5;
  int sp = blockIdx.x, qg = blockIdx.y;
  int myrow = qg * 256 + w * 32 + m;

  short8 qf[16];
#pragma unroll
  for (int kc = 0; kc < 16; ++kc)
    qf[kc] = *(const short8*)&Qb[(size_t)myrow * DE + kc * 16 + h * 8];

  float16 O[8] = {};
  float lacc = 0.f;

  short8 kreg[2], vreg[2];
#define LOAD_TILES(kb_)                                                              \
  {                                                                                  \
    int kb = (kb_);                                                                  \
    _Pragma("unroll")                                                                \
    for (int i = 0; i < 2; ++i) {                                                    \
      int c = i * 512 + tid, kr = c >> 5, kcol = c & 31;                             \
      kreg[i] = *(const short8*)&Kb[(size_t)(kb + kr) * DE + kcol * 8];              \
    }                                                                                \
    const unsigned short* vg = &Vtb[(size_t)((kb) >> 5) * 8192];                     \
    _Pragma("unroll")                                                                \
    for (int i = 0; i < 2; ++i) {                                                    \
      int c = i * 512 + tid;                                                         \
      vreg[i] = *(const short8*)&vg[c * 8];                                          \
    }                                                                                \
  }
#define STORE_TILES()                                                                \
  {                                                                                  \
    _Pragma("unroll")                                                                \
    for (int i = 0; i < 2; ++i) {                                                    \
      int c = i * 512 + tid, kr = c >> 5, kcol = c & 31;                             \
      *(short8*)&Ks[kr * 256 + ((kcol * 8) ^ ((kr & 7) << 3))] = kreg[i];            \
    }                                                                                \
    _Pragma("unroll")                                                                \
    for (int i = 0; i < 2; ++i) {                                                    \
      int c = i * 512 + tid, dr = c >> 2, dc = c & 3;                                \
      *(short8*)&Vs[dr * 40 + dc * 8] = vreg[i];                                     \
    }                                                                                \
  }

  LOAD_TILES(sp * FKPS);

  for (int it = 0; it < FIT; ++it) {
    __syncthreads();               // LDS free (previous compute done)
    STORE_TILES();
    if (it + 1 < FIT) LOAD_TILES(sp * FKPS + (it + 1) * 32);
    __syncthreads();               // LDS ready

    // QK^T with SWAPPED operands: A=K-frag, B=Q-frag -> lane (m,h) holds
    // S[k=crow(r,h)][qrow=m]: the P-row of q-row m is lane-local.
    float16 s = {};
    __builtin_amdgcn_s_setprio(1);
#pragma unroll
    for (int kc = 0; kc < 16; ++kc) {
      short8 b0 = *(const short8*)&Ks[m * 256 + ((kc * 16 + h * 8) ^ ((m & 7) << 3))];
      s = __builtin_amdgcn_mfma_f32_32x32x16_bf16(b0, qf[kc], s, 0, 0, 0);
    }
    __builtin_amdgcn_s_setprio(0);

    // p[r] = P[m][k=crow(r,h)]; exp(0.625*s - 11.0903549) == exp2(0.90168440*s - 16)
    float p[16];
#pragma unroll
    for (int r = 0; r < 16; ++r)
      p[r] = exp2f(fmaf(s[r], 0.90168440f, -16.0f));

    lacc += ((p[0] + p[1]) + (p[2] + p[3])) + ((p[4] + p[5]) + (p[6] + p[7])) +
            ((p[8] + p[9]) + (p[10] + p[11])) + ((p[12] + p[13]) + (p[14] + p[15]));

    unsigned c0 = cvtpk_bf16(p[0],  p[1]);
    unsigned c1 = cvtpk_bf16(p[2],  p[3]);
    unsigned c2 = cvtpk_bf16(p[4],  p[5]);
    unsigned c3 = cvtpk_bf16(p[6],  p[7]);
    unsigned c4 = cvtpk_bf16(p[8],  p[9]);
    unsigned c5 = cvtpk_bf16(p[10], p[11]);
    unsigned c6 = cvtpk_bf16(p[12], p[13]);
    unsigned c7 = cvtpk_bf16(p[14], p[15]);
    halfswap(c0, c2, h);
    halfswap(c1, c3, h);
    halfswap(c4, c6, h);
    halfswap(c5, c7, h);
    uint4v w0v = {c0, c1, c2, c3};
    uint4v w1v = {c4, c5, c6, c7};
    short8 pa0 = __builtin_bit_cast(short8, w0v);
    short8 pa1 = __builtin_bit_cast(short8, w1v);

    __builtin_amdgcn_s_setprio(1);
#pragma unroll
    for (int ct = 0; ct < 8; ++ct) {
      short8 vb0 = *(const short8*)&Vs[(ct * 32 + m) * 40 + h * 8];
      short8 vb1 = *(const short8*)&Vs[(ct * 32 + m) * 40 + 16 + h * 8];
      O[ct] = __builtin_amdgcn_mfma_f32_32x32x16_bf16(pa0, vb0, O[ct], 0, 0, 0);
      O[ct] = __builtin_amdgcn_mfma_f32_32x32x16_bf16(pa1, vb1, O[ct], 0, 0, 0);
    }
    __builtin_amdgcn_s_setprio(0);
  }
#undef LOAD_TILES
#undef STORE_TILES

  size_t ob = ((size_t)sp * NB + qg * 256 + w * 32) * DE;
#pragma unroll
  for (int ct = 0; ct < 8; ++ct)
#pragma unroll
    for (int r = 0; r < 16; ++r) {
      int rr = (r & 3) + 8 * (r >> 2) + 4 * h;
      Opb[ob + (size_t)rr * DE + ct * 32 + m] = f2bf(O[ct][r]);
    }
  float ltot = lacc + __shfl_xor(lacc, 32, 64);
  if (h == 0)
    Lp[sp * NB + qg * 256 + w * 32 + m] = ltot;
}

__global__ __launch_bounds__(256) void combine_kernel(const float* __restrict__ z,
                                                      const unsigned short* __restrict__ Opb,
                                                      const float* __restrict__ Lp,
                                                      float* __restrict__ out) {
  int n = blockIdx.x, c = threadIdx.x;
  float num = 0.f, den = 0.f;
#pragma unroll
  for (int s = 0; s < FSPL; ++s) {
    den += Lp[s * NB + n];
    num += bf2f(Opb[((size_t)s * NB + n) * DE + c]);
  }
  size_t base = (size_t)n * DE + c;
  out[base] = z[base] + 0.5f * num / den;
}

// ---------------- launcher: 8 launches, stream-ordered ----------------
extern "C" void kernel_launch(void* const* d_in, const int* in_sizes, int n_in,
                              void* d_out, int out_size, void* d_ws, size_t ws_size,
                              hipStream_t stream) {
  (void)in_sizes; (void)n_in; (void)out_size; (void)ws_size;
  const float* z       = (const float*)d_in[0];
  const int*   labels  = (const int*)d_in[1];
  float*       memory  = (float*)d_in[2];
  const float* weights = (const float*)d_in[3];
  const float* rmean   = (const float*)d_in[4];
  const float* rcov    = (const float*)d_in[5];
  const float* Wq      = (const float*)d_in[6];
  const float* bq      = (const float*)d_in[7];
  const float* Wk      = (const float*)d_in[8];
  const float* bk      = (const float*)d_in[9];
  const float* Wv      = (const float*)d_in[10];
  const float* bv      = (const float*)d_in[11];
  float* out = (float*)d_out;
  float* ws  = (float*)d_ws;

  unsigned short* Qbf = (unsigned short*)(ws + OFF_QB);
  unsigned short* Kbf = (unsigned short*)(ws + OFF_KB);
  unsigned short* Vtb = (unsigned short*)(ws + OFF_VTB);
  float* Lp           = ws + OFF_LP;
  unsigned short* Opb = (unsigned short*)(ws + OFF_OPB);
  float* SB    = ws + OFF_OPB;    // stats overlay (dead before flash writes Opb)
  float* A     = SB + SO_A;
  float* X     = SB + SO_X;
  float* mup   = SB + SO_MUP;
  float* dist  = SB + SO_DIST;

  mupart_kernel<<<64, 256, 0, stream>>>(z, mup, A);
  covpart_kernel<<<dim3(4, 4, 16), 256, 0, stream>>>(z, A);
  gemmx_kernel<<<dim3(16, 16), 256, 0, stream>>>(A, rcov, mup, X);
  dist_kernel<<<NB / 4, 256, 0, stream>>>(z, rmean, mup, X, dist);
  update_kernel<<<1, 1024, 0, stream>>>(dist, labels, weights, z, memory);
  qkv_kernel<<<1088, 256, 0, stream>>>(z, memory, Wq, bq, Wk, bk, Wv, bv, Qbf, Kbf, Vtb);
  flash_kernel<<<dim3(FSPL, NB / 256), 512, 0, stream>>>(Qbf, Kbf, Vtb, Opb, Lp);
  combine_kernel<<<NB, 256, 0, stream>>>(z, Opb, Lp, out);
}

// Round 11
// 242.110 us; speedup vs baseline: 1.0600x; 1.0600x over previous
//
#include <hip/hip_runtime.h>
#include <math.h>

#define NB   2048
#define DE   256
#define MEMN 16384
#define CAND_CAP 256
#define FSPL 32
#define FKPS 512
#define FIT  16   // 16 iters x 32 K-rows

typedef __attribute__((ext_vector_type(8)))  short  short8;
typedef __attribute__((ext_vector_type(16))) float  float16;
typedef __attribute__((ext_vector_type(4)))  unsigned uint4v;
typedef __attribute__((ext_vector_type(2)))  unsigned uint2v;

// ---------------- workspace layout (float element offsets), ~51.6 MB (verified fit, round 3) ----------------
static const size_t OFF_QB   = 0;          // 2048*256 bf16
static const size_t OFF_KB   = 262144;     // 16384*256 bf16
static const size_t OFF_VTB  = 2359296;    // Vt tiled [512][256][32] bf16
static const size_t OFF_LP   = 4456448;    // 32*2048 floats
static const size_t OFF_OPB  = 4521984;    // 32*2048*256 bf16
// stats overlay (dead before flash writes Opb), relative to OFF_OPB:
static const size_t SO_A    = 0;
static const size_t SO_X    = 65536;
static const size_t SO_MUP  = 131072;
static const size_t SO_DIST = 147456;

__device__ inline unsigned short f2bf(float f) {
  unsigned u = __float_as_uint(f);
  unsigned r = (u + 0x7fffu + ((u >> 16) & 1u)) >> 16;
  return (unsigned short)r;
}
__device__ inline float bf2f(unsigned short s) {
  return __uint_as_float((unsigned)s << 16);
}

// pack two f32 -> one u32 of 2x bf16 (RNE, lo in [15:0]) — bit-identical to f2bf pairs
__device__ inline unsigned cvtpk_bf16(float lo, float hi) {
  unsigned r;
  asm("v_cvt_pk_bf16_f32 %0, %1, %2" : "=v"(r) : "v"(lo), "v"(hi));
  return r;
}
// pack 8 f32 (two float4) into a short8 of bf16 via 4 cvt_pk ops
__device__ inline short8 pack8_bf16(float4 f0, float4 f1) {
  uint4v u = {cvtpk_bf16(f0.x, f0.y), cvtpk_bf16(f0.z, f0.w),
              cvtpk_bf16(f1.x, f1.y), cvtpk_bf16(f1.z, f1.w)};
  return __builtin_bit_cast(short8, u);
}

// exchange lane-halves between a lower-k word and a higher-k word (T12).
__device__ inline void halfswap(unsigned& lo, unsigned& hi, int h) {
#if __has_builtin(__builtin_amdgcn_permlane32_swap)
  (void)h;
  uint2v r = __builtin_amdgcn_permlane32_swap(lo, hi, false, false);
  lo = r.x; hi = r.y;
#else
  unsigned a = (unsigned)__shfl_xor((int)lo, 32, 64);
  unsigned b = (unsigned)__shfl_xor((int)hi, 32, 64);
  unsigned nlo = (h == 0) ? lo : b;
  unsigned nhi = (h == 0) ? a  : hi;
  lo = nlo; hi = nhi;
#endif
}

__device__ inline void bitonic_sort_u64(unsigned long long* key, int n, int tid, int nth) {
  for (int k = 2; k <= n; k <<= 1) {
    for (int j = k >> 1; j > 0; j >>= 1) {
      __syncthreads();
      for (int i = tid; i < n; i += nth) {
        int ixj = i ^ j;
        if (ixj > i) {
          unsigned long long a = key[i], b = key[ixj];
          bool up = ((i & k) == 0);
          if ((a > b) == up) { key[i] = b; key[ixj] = a; }
        }
      }
    }
  }
  __syncthreads();
}

// ---------------- mean partials (also zeroes A for covpart's atomics) ----------------
__global__ __launch_bounds__(256) void mupart_kernel(const float* __restrict__ z,
                                                     float* __restrict__ mup,
                                                     float* __restrict__ Az) {
  int d = threadIdx.x;
  int r0 = blockIdx.x * 32;
  float4 zero4 = {0.f, 0.f, 0.f, 0.f};
  *(float4*)&Az[(size_t)blockIdx.x * 1024 + threadIdx.x * 4] = zero4;
  float s = 0.f;
  for (int r = 0; r < 32; ++r) s += z[(size_t)(r0 + r) * DE + d];
  mup[blockIdx.x * DE + d] = s;
}

// ---------------- raw second-moment partials: Z^T Z over 128-row slice, atomicAdd into A ----------------
__global__ __launch_bounds__(256) void covpart_kernel(const float* __restrict__ z,
                                                      float* __restrict__ A) {
  __shared__ float As[16][68];
  __shared__ float Bs[16][68];
  int tid = threadIdx.x, tx = tid & 15, ty = tid >> 4;
  int i0 = blockIdx.x * 64, j0 = blockIdx.y * 64;
  int nbase = blockIdx.z * 128;
  float acc[4][4] = {};
  for (int nt = 0; nt < 8; ++nt) {
    int n0 = nbase + nt * 16;
    for (int e = tid; e < 1024; e += 256) {
      int c = e & 63, nn = e >> 6;
      As[nn][c] = z[(size_t)(n0 + nn) * DE + i0 + c];
      Bs[nn][c] = z[(size_t)(n0 + nn) * DE + j0 + c];
    }
    __syncthreads();
#pragma unroll
    for (int nn = 0; nn < 16; ++nn) {
      float4 a4 = *(const float4*)&As[nn][ty * 4];
      float4 b4 = *(const float4*)&Bs[nn][tx * 4];
      acc[0][0] += a4.x*b4.x; acc[0][1] += a4.x*b4.y; acc[0][2] += a4.x*b4.z; acc[0][3] += a4.x*b4.w;
      acc[1][0] += a4.y*b4.x; acc[1][1] += a4.y*b4.y; acc[1][2] += a4.y*b4.z; acc[1][3] += a4.y*b4.w;
      acc[2][0] += a4.z*b4.x; acc[2][1] += a4.z*b4.y; acc[2][2] += a4.z*b4.z; acc[2][3] += a4.z*b4.w;
      acc[3][0] += a4.w*b4.x; acc[3][1] += a4.w*b4.y; acc[3][2] += a4.w*b4.z; acc[3][3] += a4.w*b4.w;
    }
    __syncthreads();
  }
  for (int r = 0; r < 4; ++r) {
    int i = i0 + ty * 4 + r;
    for (int c = 0; c < 4; ++c) {
      int j = j0 + tx * 4 + c;
      atomicAdd(&A[(size_t)i * DE + j], acc[r][c]);
    }
  }
}

// ---------------- X = I + E + E^2 (E = I - A), E built on-the-fly ----------------
__global__ __launch_bounds__(256) void gemmx_kernel(const float* __restrict__ ZtZ,
                                                    const float* __restrict__ rcov,
                                                    const float* __restrict__ mup,
                                                    float* __restrict__ X) {
  __shared__ float Ea[16][17];
  __shared__ float Eb[16][17];
  __shared__ float mus[256];
  int t = threadIdx.x, tx = t & 15, ty = t >> 4;
  int i0 = blockIdx.x * 16, j0 = blockIdx.y * 16;
  {
    float s = 0.f;
    for (int b = 0; b < 64; ++b) s += mup[b * DE + t];
    mus[t] = s;   // raw column sums of z
  }
  __syncthreads();
  const float c1 = 0.01f / (float)(NB - 1);
  const float invN = 1.0f / (float)NB;
  float acc = 0.f;
  for (int k0 = 0; k0 < 256; k0 += 16) {
    int c = k0 + tx;
    {
      int r = i0 + ty;
      float base = 0.99f * rcov[(size_t)r * DE + c] +
                   c1 * (ZtZ[(size_t)r * DE + c] - mus[r] * mus[c] * invN);
      float e = -base;
      if (r == c) e += 1.0f - 1e-6f;
      Ea[ty][tx] = e;
    }
    {
      int r = j0 + ty;
      float base = 0.99f * rcov[(size_t)r * DE + c] +
                   c1 * (ZtZ[(size_t)r * DE + c] - mus[r] * mus[c] * invN);
      float e = -base;
      if (r == c) e += 1.0f - 1e-6f;
      Eb[ty][tx] = e;
    }
    __syncthreads();
#pragma unroll
    for (int k = 0; k < 16; ++k) acc += Ea[ty][k] * Eb[tx][k];   // E symmetric
    __syncthreads();
  }
  int r = i0 + ty, c = j0 + tx;
  float base = 0.99f * rcov[(size_t)r * DE + c] +
               c1 * (ZtZ[(size_t)r * DE + c] - mus[r] * mus[c] * invN);
  float e = -base;
  if (r == c) e += 1.0f - 1e-6f;
  X[(size_t)r * DE + c] = acc + e + ((r == c) ? 1.0f : 0.0f);
}

// dist: 4 rows per block, grid 512; rm = 0.99*rmean + 0.01*(sum mup)/N
__global__ __launch_bounds__(256) void dist_kernel(const float* __restrict__ z,
                                                   const float* __restrict__ rmean,
                                                   const float* __restrict__ mup,
                                                   const float* __restrict__ X,
                                                   float* __restrict__ dist) {
  __shared__ float cc[4][256];
  __shared__ float4 red[256];
  int n0 = blockIdx.x * 4, i = threadIdx.x;
  float s = 0.f;
  for (int b = 0; b < 64; ++b) s += mup[b * DE + i];
  float rmi = 0.99f * rmean[i] + 0.01f * s * (1.0f / (float)NB);
#pragma unroll
  for (int r = 0; r < 4; ++r) cc[r][i] = z[(size_t)(n0 + r) * DE + i] - rmi;
  __syncthreads();
  float y0 = 0.f, y1 = 0.f, y2 = 0.f, y3 = 0.f;
#pragma unroll 8
  for (int j = 0; j < DE; ++j) {
    float x = X[(size_t)j * DE + i];
    y0 += x * cc[0][j]; y1 += x * cc[1][j]; y2 += x * cc[2][j]; y3 += x * cc[3][j];
  }
  float4 v;
  v.x = y0 * cc[0][i]; v.y = y1 * cc[1][i]; v.z = y2 * cc[2][i]; v.w = y3 * cc[3][i];
  red[i] = v;
  __syncthreads();
  for (int sH = 128; sH > 0; sH >>= 1) {
    if (i < sH) {
      float4 a = red[i], b = red[i + sH];
      a.x += b.x; a.y += b.y; a.z += b.z; a.w += b.w;
      red[i] = a;
    }
    __syncthreads();
  }
  if (i < 4) {
    float4 tt = red[0];
    float d = (i == 0) ? tt.x : (i == 1) ? tt.y : (i == 2) ? tt.z : tt.w;
    dist[n0 + i] = sqrtf(fmaxf(d, 1e-8f));
  }
}

// ---------------- fused update: wave reductions, small-C wave sort, two-level extraction ----------------
__global__ __launch_bounds__(1024) void update_kernel(const float* __restrict__ dist,
                                                      const int* __restrict__ labels,
                                                      const float* __restrict__ weights,
                                                      const float* __restrict__ z,
                                                      float* __restrict__ memory) {
  __shared__ unsigned long long ikeys[NB];
  __shared__ unsigned long long ck[CAND_CAP];
  __shared__ unsigned long long gmin[16];
  __shared__ int slots[CAND_CAP], srcs[CAND_CAP];
  __shared__ float smin[16], smax[16];
  __shared__ int scnt[16];
  __shared__ float s_kl, s_dmin, s_inv;
  __shared__ int s_ccnt, s_m, s_stop, s_bg;
  int t = threadIdx.x;
  int wid = t >> 6, lane = t & 63;

  float mn = 1e30f, mx = -1e30f; int c1 = 0;
  for (int n = t; n < NB; n += 1024) {
    float d = dist[n];
    mn = fminf(mn, d); mx = fmaxf(mx, d);
    c1 += labels[n];
  }
#pragma unroll
  for (int o = 32; o > 0; o >>= 1) {
    mn = fminf(mn, __shfl_xor(mn, o, 64));
    mx = fmaxf(mx, __shfl_xor(mx, o, 64));
    c1 += __shfl_xor(c1, o, 64);
  }
  if (lane == 0) { smin[wid] = mn; smax[wid] = mx; scnt[wid] = c1; }
  if (t == 0) { s_ccnt = 0; s_m = 0; s_stop = 0; }
  __syncthreads();
  if (t == 0) {
    float a = 1e30f, b = -1e30f; int cc = 0;
    for (int i = 0; i < 16; ++i) { a = fminf(a, smin[i]); b = fmaxf(b, smax[i]); cc += scnt[i]; }
    float p1 = (float)cc / (float)NB;
    float p0 = (float)(NB - cc) / (float)NB;
    float kl = p0 * logf(fmaxf(2.f * p0, 1e-8f)) + p1 * logf(fmaxf(2.f * p1, 1e-8f));
    s_kl = fmaxf(kl, 0.f);
    s_dmin = a;
    s_inv = 1.0f / (b - a + 1e-8f);
  }
  __syncthreads();
  float kl = s_kl;

  for (int n = t; n < NB; n += 1024) {
    float imp = (1.0f + (dist[n] - s_dmin) * s_inv) * kl;
    ikeys[n] = ((unsigned long long)(unsigned)(~__float_as_uint(imp)) << 32) | (unsigned)n;
  }
  float thresh = 2.f * kl;
  for (int j = t; j < MEMN; j += 1024) {
    float wv = weights[j];
    if (wv < thresh) {
      int p = atomicAdd(&s_ccnt, 1);
      if (p < CAND_CAP) ck[p] = ((unsigned long long)__float_as_uint(wv) << 32) | (unsigned)j;
    }
  }
  __syncthreads();
  int C = s_ccnt; if (C > CAND_CAP) C = CAND_CAP;
  for (int i = t; i < CAND_CAP; i += 1024)
    if (i >= C) ck[i] = 0xFFFFFFFFFFFFFFFFULL;
  __syncthreads();
  if (C <= 64) {
    // single-wave rank sort, no barriers inside (wave 0 only)
    if (wid == 0) {
      unsigned long long key = (lane < C) ? ck[lane] : 0xFFFFFFFFFFFFFFFFULL;
      int rank = 0;
      for (int j = 0; j < 64; ++j) {
        unsigned long long o = (unsigned long long)__shfl((long long)key, j, 64);
        rank += (o < key) || (o == key && j < lane);
      }
      if (lane < C) ck[rank] = key;
    }
    __syncthreads();
  } else {
    bitonic_sort_u64(ck, CAND_CAP, t, 1024);
  }

  // group minima: wave wid owns ikeys[wid*128 .. wid*128+127]
  {
    unsigned long long a = ikeys[wid * 128 + lane];
    unsigned long long b = ikeys[wid * 128 + 64 + lane];
    unsigned long long mm = a < b ? a : b;
#pragma unroll
    for (int o = 32; o > 0; o >>= 1) {
      unsigned long long ot = (unsigned long long)__shfl_xor((long long)mm, o, 64);
      if (ot < mm) mm = ot;
    }
    if (lane == 0) gmin[wid] = mm;
  }
  __syncthreads();

  float prevv = 0.f;   // thread 0 only
  for (int i = 0; i < C; ++i) {
    if (t == 0) {
      unsigned long long best = 0xFFFFFFFFFFFFFFFFULL;
      for (int g = 0; g < 16; ++g) if (gmin[g] < best) best = gmin[g];
      float im = __uint_as_float(~(unsigned)(best >> 32));
      float wv = __uint_as_float((unsigned)(ck[i] >> 32));
      bool ok = (im > wv) && (i == 0 || prevv >= wv);
      if (ok) {
        int idx = (int)(best & 0xffffffffULL);
        slots[s_m] = (int)(ck[i] & 0xffffffffULL);
        srcs[s_m]  = idx;
        s_m++;
        prevv = im;
        ikeys[idx] = 0xFFFFFFFFFFFFFFFFULL;
        s_bg = idx >> 7;
      } else {
        s_stop = 1; s_bg = -1;
      }
    }
    __syncthreads();
    if (s_stop) break;
    if (wid == s_bg) {
      unsigned long long a = ikeys[wid * 128 + lane];
      unsigned long long b = ikeys[wid * 128 + 64 + lane];
      unsigned long long mm = a < b ? a : b;
#pragma unroll
      for (int o = 32; o > 0; o >>= 1) {
        unsigned long long ot = (unsigned long long)__shfl_xor((long long)mm, o, 64);
        if (ot < mm) mm = ot;
      }
      if (lane == 0) gmin[wid] = mm;
    }
    __syncthreads();
  }
  int m = s_m;
  for (int e = t; e < m * DE; e += 1024) {
    int i = e >> 8, d = e & 255;
    memory[(size_t)slots[i] * DE + d] = z[(size_t)srcs[i] * DE + d];
  }
}

// ---------------- fused Q/K/V projection GEMMs (one launch, role by flat block id) ----------------
// bf16 packing via v_cvt_pk_bf16_f32 (2 elems/op, RNE, bit-identical to f2bf pairs).
__global__ __launch_bounds__(256, 1) void qkv_kernel(
    const float* __restrict__ z, const float* __restrict__ memory,
    const float* __restrict__ Wq, const float* __restrict__ bq,
    const float* __restrict__ Wk, const float* __restrict__ bk,
    const float* __restrict__ Wv, const float* __restrict__ bv,
    unsigned short* __restrict__ Qbf, unsigned short* __restrict__ Kbf,
    unsigned short* __restrict__ Vtb) {
  __shared__ unsigned short Bsh[64 * 264];
  int flat = blockIdx.x;
  const float *Af, *Bf, *bias;
  unsigned short* C;
  int bias_row, vtile, gx, gy, ldC;
  if (flat < 64) {                 // Q = z@Wq^T+bq
    gx = flat & 15; gy = flat >> 4;
    Af = z; Bf = Wq; bias = bq; bias_row = 0; vtile = 0; C = Qbf; ldC = DE;
  } else if (flat < 576) {         // K = mem@Wk^T+bk
    int f = flat - 64; gx = f & 127; gy = f >> 7;
    Af = memory; Bf = Wk; bias = bk; bias_row = 0; vtile = 0; C = Kbf; ldC = DE;
  } else {                         // Vt = Wv@mem^T+bv, tiled output
    int f = flat - 576; gx = f & 1; gy = f >> 1;
    Af = Wv; Bf = memory; bias = bv; bias_row = 1; vtile = 1; C = Vtb; ldC = 0;
  }

  int tid = threadIdx.x;
  int w = tid >> 6, lane = tid & 63;
  int m = lane & 31, h = lane >> 5;
  int arow = gx * 128 + w * 32 + m;
  int n0 = gy * 64;

  short8 af[16];
#pragma unroll
  for (int kc = 0; kc < 16; ++kc) {
    const float* src = &Af[(size_t)arow * DE + kc * 16 + h * 8];
    float4 f0 = *(const float4*)&src[0];
    float4 f1 = *(const float4*)&src[4];
    af[kc] = pack8_bf16(f0, f1);
  }
  {
    int r = tid >> 2, q = tid & 3;
    const float* src = &Bf[(size_t)(n0 + r) * DE + q * 64];
    unsigned short* dst = &Bsh[r * 264 + q * 64];
#pragma unroll
    for (int j = 0; j < 8; ++j) {
      float4 f0 = *(const float4*)&src[j * 8];
      float4 f1 = *(const float4*)&src[j * 8 + 4];
      *(short8*)&dst[j * 8] = pack8_bf16(f0, f1);
    }
  }
  __syncthreads();

  float16 a0 = {}, a1 = {};
#pragma unroll
  for (int kc = 0; kc < 16; ++kc) {
    short8 b0 = *(const short8*)&Bsh[(0 * 32 + m) * 264 + kc * 16 + h * 8];
    short8 b1 = *(const short8*)&Bsh[(1 * 32 + m) * 264 + kc * 16 + h * 8];
    a0 = __builtin_amdgcn_mfma_f32_32x32x16_bf16(af[kc], b0, a0, 0, 0, 0);
    a1 = __builtin_amdgcn_mfma_f32_32x32x16_bf16(af[kc], b1, a1, 0, 0, 0);
  }
#pragma unroll
  for (int r = 0; r < 16; ++r) {
    int rr = (r & 3) + 8 * (r >> 2) + 4 * h;
    int orow = gx * 128 + w * 32 + rr;
    int oc0 = n0 + m, oc1 = n0 + 32 + m;
    float bb0 = bias_row ? bias[orow] : bias[oc0];
    float bb1 = bias_row ? bias[orow] : bias[oc1];
    if (!vtile) {
      C[(size_t)orow * ldC + oc0] = f2bf(a0[r] + bb0);
      C[(size_t)orow * ldC + oc1] = f2bf(a1[r] + bb1);
    } else {
      C[(size_t)(oc0 >> 5) * 8192 + (size_t)orow * 32 + (oc0 & 31)] = f2bf(a0[r] + bb0);
      C[(size_t)(oc1 >> 5) * 8192 + (size_t)orow * 32 + (oc1 & 31)] = f2bf(a1[r] + bb1);
    }
  }
}

// ---------------- MFMA flash attention: dh-merged, FSPL=32, T12 in-reg softmax ----------------
// ROUND-9 STRUCTURE RESTORED (46.3 us, best measured). Round-10's XOR-swizzle on
// an unpadded 256-stride Ks REGRESSED 5x on bank conflicts: m*256 el = 512 B ==
// 0 mod 32 banks, so lanes m, m+8, m+16, m+24 share a bank at different addrs.
// The 264-pad (m*264 el -> 4-bank rotation per row) is the better layout here.
__global__ __launch_bounds__(512, 2) void flash_kernel(
    const unsigned short* __restrict__ Qb, const unsigned short* __restrict__ Kb,
    const unsigned short* __restrict__ Vtb, unsigned short* __restrict__ Opb,
    float* __restrict__ Lp) {
  __shared__ unsigned short Ks[32 * 264];
  __shared__ unsigned short Vs[256 * 40];

  int tid = threadIdx.x;
  int w = tid >> 6, lane = tid & 63;
  int m = lane & 31, h = lane >> 5;
  int sp = blockIdx.x, qg = blockIdx.y;
  int myrow = qg * 256 + w * 32 + m;

  short8 qf[16];
#pragma unroll
  for (int kc = 0; kc < 16; ++kc)
    qf[kc] = *(const short8*)&Qb[(size_t)myrow * DE + kc * 16 + h * 8];

  float16 O[8] = {};
  float lacc = 0.f;

  short8 kreg[2], vreg[2];
#define LOAD_TILES(kb_)                                                              \
  {                                                                                  \
    int kb = (kb_);                                                                  \
    _Pragma("unroll")                                                                \
    for (int i = 0; i < 2; ++i) {                                                    \
      int c = i * 512 + tid, kr = c >> 5, kcol = c & 31;                             \
      kreg[i] = *(const short8*)&Kb[(size_t)(kb + kr) * DE + kcol * 8];              \
    }                                                                                \
    const unsigned short* vg = &Vtb[(size_t)((kb) >> 5) * 8192];                     \
    _Pragma("unroll")                                                                \
    for (int i = 0; i < 2; ++i) {                                                    \
      int c = i * 512 + tid;                                                         \
      vreg[i] = *(const short8*)&vg[c * 8];                                          \
    }                                                                                \
  }
#define STORE_TILES()                                                                \
  {                                                                                  \
    _Pragma("unroll")                                                                \
    for (int i = 0; i < 2; ++i) {                                                    \
      int c = i * 512 + tid, kr = c >> 5, kcol = c & 31;                             \
      *(short8*)&Ks[kr * 264 + kcol * 8] = kreg[i];                                  \
    }                                                                                \
    _Pragma("unroll")                                                                \
    for (int i = 0; i < 2; ++i) {                                                    \
      int c = i * 512 + tid, dr = c >> 2, dc = c & 3;                                \
      *(short8*)&Vs[dr * 40 + dc * 8] = vreg[i];                                     \
    }                                                                                \
  }

  LOAD_TILES(sp * FKPS);

  for (int it = 0; it < FIT; ++it) {
    __syncthreads();               // LDS free (previous compute done)
    STORE_TILES();
    if (it + 1 < FIT) LOAD_TILES(sp * FKPS + (it + 1) * 32);
    __syncthreads();               // LDS ready

    // QK^T with SWAPPED operands: A=K-frag, B=Q-frag -> lane (m,h) holds
    // S[k=crow(r,h)][qrow=m]: the P-row of q-row m is lane-local.
    float16 s = {};
    __builtin_amdgcn_s_setprio(1);
#pragma unroll
    for (int kc = 0; kc < 16; ++kc) {
      short8 b0 = *(const short8*)&Ks[m * 264 + kc * 16 + h * 8];
      s = __builtin_amdgcn_mfma_f32_32x32x16_bf16(b0, qf[kc], s, 0, 0, 0);
    }
    __builtin_amdgcn_s_setprio(0);

    // p[r] = P[m][k=crow(r,h)]; exp(0.625*s - 11.0903549) == exp2(0.90168440*s - 16)
    float p[16];
#pragma unroll
    for (int r = 0; r < 16; ++r)
      p[r] = exp2f(fmaf(s[r], 0.90168440f, -16.0f));

    lacc += ((p[0] + p[1]) + (p[2] + p[3])) + ((p[4] + p[5]) + (p[6] + p[7])) +
            ((p[8] + p[9]) + (p[10] + p[11])) + ((p[12] + p[13]) + (p[14] + p[15]));

    unsigned c0 = cvtpk_bf16(p[0],  p[1]);
    unsigned c1 = cvtpk_bf16(p[2],  p[3]);
    unsigned c2 = cvtpk_bf16(p[4],  p[5]);
    unsigned c3 = cvtpk_bf16(p[6],  p[7]);
    unsigned c4 = cvtpk_bf16(p[8],  p[9]);
    unsigned c5 = cvtpk_bf16(p[10], p[11]);
    unsigned c6 = cvtpk_bf16(p[12], p[13]);
    unsigned c7 = cvtpk_bf16(p[14], p[15]);
    halfswap(c0, c2, h);
    halfswap(c1, c3, h);
    halfswap(c4, c6, h);
    halfswap(c5, c7, h);
    uint4v w0v = {c0, c1, c2, c3};
    uint4v w1v = {c4, c5, c6, c7};
    short8 pa0 = __builtin_bit_cast(short8, w0v);
    short8 pa1 = __builtin_bit_cast(short8, w1v);

    __builtin_amdgcn_s_setprio(1);
#pragma unroll
    for (int ct = 0; ct < 8; ++ct) {
      short8 vb0 = *(const short8*)&Vs[(ct * 32 + m) * 40 + h * 8];
      short8 vb1 = *(const short8*)&Vs[(ct * 32 + m) * 40 + 16 + h * 8];
      O[ct] = __builtin_amdgcn_mfma_f32_32x32x16_bf16(pa0, vb0, O[ct], 0, 0, 0);
      O[ct] = __builtin_amdgcn_mfma_f32_32x32x16_bf16(pa1, vb1, O[ct], 0, 0, 0);
    }
    __builtin_amdgcn_s_setprio(0);
  }
#undef LOAD_TILES
#undef STORE_TILES

  size_t ob = ((size_t)sp * NB + qg * 256 + w * 32) * DE;
#pragma unroll
  for (int ct = 0; ct < 8; ++ct)
#pragma unroll
    for (int r = 0; r < 16; ++r) {
      int rr = (r & 3) + 8 * (r >> 2) + 4 * h;
      Opb[ob + (size_t)rr * DE + ct * 32 + m] = f2bf(O[ct][r]);
    }
  float ltot = lacc + __shfl_xor(lacc, 32, 64);
  if (h == 0)
    Lp[sp * NB + qg * 256 + w * 32 + m] = ltot;
}

__global__ __launch_bounds__(256) void combine_kernel(const float* __restrict__ z,
                                                      const unsigned short* __restrict__ Opb,
                                                      const float* __restrict__ Lp,
                                                      float* __restrict__ out) {
  int n = blockIdx.x, c = threadIdx.x;
  float num = 0.f, den = 0.f;
#pragma unroll
  for (int s = 0; s < FSPL; ++s) {
    den += Lp[s * NB + n];
    num += bf2f(Opb[((size_t)s * NB + n) * DE + c]);
  }
  size_t base = (size_t)n * DE + c;
  out[base] = z[base] + 0.5f * num / den;
}

// ---------------- launcher: 8 launches, stream-ordered ----------------
extern "C" void kernel_launch(void* const* d_in, const int* in_sizes, int n_in,
                              void* d_out, int out_size, void* d_ws, size_t ws_size,
                              hipStream_t stream) {
  (void)in_sizes; (void)n_in; (void)out_size; (void)ws_size;
  const float* z       = (const float*)d_in[0];
  const int*   labels  = (const int*)d_in[1];
  float*       memory  = (float*)d_in[2];
  const float* weights = (const float*)d_in[3];
  const float* rmean   = (const float*)d_in[4];
  const float* rcov    = (const float*)d_in[5];
  const float* Wq      = (const float*)d_in[6];
  const float* bq      = (const float*)d_in[7];
  const float* Wk      = (const float*)d_in[8];
  const float* bk      = (const float*)d_in[9];
  const float* Wv      = (const float*)d_in[10];
  const float* bv      = (const float*)d_in[11];
  float* out = (float*)d_out;
  float* ws  = (float*)d_ws;

  unsigned short* Qbf = (unsigned short*)(ws + OFF_QB);
  unsigned short* Kbf = (unsigned short*)(ws + OFF_KB);
  unsigned short* Vtb = (unsigned short*)(ws + OFF_VTB);
  float* Lp           = ws + OFF_LP;
  unsigned short* Opb = (unsigned short*)(ws + OFF_OPB);
  float* SB    = ws + OFF_OPB;    // stats overlay (dead before flash writes Opb)
  float* A     = SB + SO_A;
  float* X     = SB + SO_X;
  float* mup   = SB + SO_MUP;
  float* dist  = SB + SO_DIST;

  mupart_kernel<<<64, 256, 0, stream>>>(z, mup, A);
  covpart_kernel<<<dim3(4, 4, 16), 256, 0, stream>>>(z, A);
  gemmx_kernel<<<dim3(16, 16), 256, 0, stream>>>(A, rcov, mup, X);
  dist_kernel<<<NB / 4, 256, 0, stream>>>(z, rmean, mup, X, dist);
  update_kernel<<<1, 1024, 0, stream>>>(dist, labels, weights, z, memory);
  qkv_kernel<<<1088, 256, 0, stream>>>(z, memory, Wq, bq, Wk, bk, Wv, bv, Qbf, Kbf, Vtb);
  flash_kernel<<<dim3(FSPL, NB / 256), 512, 0, stream>>>(Qbf, Kbf, Vtb, Opb, Lp);
  combine_kernel<<<NB, 256, 0, stream>>>(z, Opb, Lp, out);
}

// Round 12
// 227.225 us; speedup vs baseline: 1.1294x; 1.0655x over previous
//
#include <hip/hip_runtime.h>
#include <math.h>

#define NB   2048
#define DE   256
#define MEMN 16384
#define CAND_CAP 256
#define FSPL 32
#define FKPS 512
#define FIT  16   // 16 iters x 32 K-rows

typedef __attribute__((ext_vector_type(8)))  short  short8;
typedef __attribute__((ext_vector_type(16))) float  float16;
typedef __attribute__((ext_vector_type(4)))  unsigned uint4v;
typedef __attribute__((ext_vector_type(2)))  unsigned uint2v;

// ---------------- workspace layout (float element offsets), ~51.6 MB (verified fit, round 3) ----------------
static const size_t OFF_QB   = 0;          // 2048*256 bf16
static const size_t OFF_KB   = 262144;     // 16384*256 bf16
static const size_t OFF_VTB  = 2359296;    // Vt tiled [512][256][32] bf16
static const size_t OFF_LP   = 4456448;    // 32*2048 floats
static const size_t OFF_OPB  = 4521984;    // 32*2048*256 bf16
// stats overlay (dead before flash writes Opb), relative to OFF_OPB:
static const size_t SO_A    = 0;
static const size_t SO_X    = 65536;
static const size_t SO_MUP  = 131072;
static const size_t SO_DIST = 147456;

__device__ inline unsigned short f2bf(float f) {
  unsigned u = __float_as_uint(f);
  unsigned r = (u + 0x7fffu + ((u >> 16) & 1u)) >> 16;
  return (unsigned short)r;
}
__device__ inline float bf2f(unsigned short s) {
  return __uint_as_float((unsigned)s << 16);
}

// pack two f32 -> one u32 of 2x bf16 (RNE, lo in [15:0]) — bit-identical to f2bf pairs
__device__ inline unsigned cvtpk_bf16(float lo, float hi) {
  unsigned r;
  asm("v_cvt_pk_bf16_f32 %0, %1, %2" : "=v"(r) : "v"(lo), "v"(hi));
  return r;
}
// pack 8 f32 (two float4) into a short8 of bf16 via 4 cvt_pk ops
__device__ inline short8 pack8_bf16(float4 f0, float4 f1) {
  uint4v u = {cvtpk_bf16(f0.x, f0.y), cvtpk_bf16(f0.z, f0.w),
              cvtpk_bf16(f1.x, f1.y), cvtpk_bf16(f1.z, f1.w)};
  return __builtin_bit_cast(short8, u);
}

// exchange lane-halves between a lower-k word and a higher-k word (T12).
__device__ inline void halfswap(unsigned& lo, unsigned& hi, int h) {
#if __has_builtin(__builtin_amdgcn_permlane32_swap)
  (void)h;
  uint2v r = __builtin_amdgcn_permlane32_swap(lo, hi, false, false);
  lo = r.x; hi = r.y;
#else
  unsigned a = (unsigned)__shfl_xor((int)lo, 32, 64);
  unsigned b = (unsigned)__shfl_xor((int)hi, 32, 64);
  unsigned nlo = (h == 0) ? lo : b;
  unsigned nhi = (h == 0) ? a  : hi;
  lo = nlo; hi = nhi;
#endif
}

__device__ inline void bitonic_sort_u64(unsigned long long* key, int n, int tid, int nth) {
  for (int k = 2; k <= n; k <<= 1) {
    for (int j = k >> 1; j > 0; j >>= 1) {
      __syncthreads();
      for (int i = tid; i < n; i += nth) {
        int ixj = i ^ j;
        if (ixj > i) {
          unsigned long long a = key[i], b = key[ixj];
          bool up = ((i & k) == 0);
          if ((a > b) == up) { key[i] = b; key[ixj] = a; }
        }
      }
    }
  }
  __syncthreads();
}

// ---------------- mean partials (also zeroes A for covpart's atomics) ----------------
__global__ __launch_bounds__(256) void mupart_kernel(const float* __restrict__ z,
                                                     float* __restrict__ mup,
                                                     float* __restrict__ Az) {
  int d = threadIdx.x;
  int r0 = blockIdx.x * 32;
  float4 zero4 = {0.f, 0.f, 0.f, 0.f};
  *(float4*)&Az[(size_t)blockIdx.x * 1024 + threadIdx.x * 4] = zero4;
  float s = 0.f;
  for (int r = 0; r < 32; ++r) s += z[(size_t)(r0 + r) * DE + d];
  mup[blockIdx.x * DE + d] = s;
}

// ---------------- raw second-moment partials: Z^T Z over 128-row slice, atomicAdd into A ----------------
__global__ __launch_bounds__(256) void covpart_kernel(const float* __restrict__ z,
                                                      float* __restrict__ A) {
  __shared__ float As[16][68];
  __shared__ float Bs[16][68];
  int tid = threadIdx.x, tx = tid & 15, ty = tid >> 4;
  int i0 = blockIdx.x * 64, j0 = blockIdx.y * 64;
  int nbase = blockIdx.z * 128;
  float acc[4][4] = {};
  for (int nt = 0; nt < 8; ++nt) {
    int n0 = nbase + nt * 16;
    for (int e = tid; e < 1024; e += 256) {
      int c = e & 63, nn = e >> 6;
      As[nn][c] = z[(size_t)(n0 + nn) * DE + i0 + c];
      Bs[nn][c] = z[(size_t)(n0 + nn) * DE + j0 + c];
    }
    __syncthreads();
#pragma unroll
    for (int nn = 0; nn < 16; ++nn) {
      float4 a4 = *(const float4*)&As[nn][ty * 4];
      float4 b4 = *(const float4*)&Bs[nn][tx * 4];
      acc[0][0] += a4.x*b4.x; acc[0][1] += a4.x*b4.y; acc[0][2] += a4.x*b4.z; acc[0][3] += a4.x*b4.w;
      acc[1][0] += a4.y*b4.x; acc[1][1] += a4.y*b4.y; acc[1][2] += a4.y*b4.z; acc[1][3] += a4.y*b4.w;
      acc[2][0] += a4.z*b4.x; acc[2][1] += a4.z*b4.y; acc[2][2] += a4.z*b4.z; acc[2][3] += a4.z*b4.w;
      acc[3][0] += a4.w*b4.x; acc[3][1] += a4.w*b4.y; acc[3][2] += a4.w*b4.z; acc[3][3] += a4.w*b4.w;
    }
    __syncthreads();
  }
  for (int r = 0; r < 4; ++r) {
    int i = i0 + ty * 4 + r;
    for (int c = 0; c < 4; ++c) {
      int j = j0 + tx * 4 + c;
      atomicAdd(&A[(size_t)i * DE + j], acc[r][c]);
    }
  }
}

// ---------------- X = I + E + E^2 (E = I - A), E built on-the-fly ----------------
__global__ __launch_bounds__(256) void gemmx_kernel(const float* __restrict__ ZtZ,
                                                    const float* __restrict__ rcov,
                                                    const float* __restrict__ mup,
                                                    float* __restrict__ X) {
  __shared__ float Ea[16][17];
  __shared__ float Eb[16][17];
  __shared__ float mus[256];
  int t = threadIdx.x, tx = t & 15, ty = t >> 4;
  int i0 = blockIdx.x * 16, j0 = blockIdx.y * 16;
  {
    float s = 0.f;
    for (int b = 0; b < 64; ++b) s += mup[b * DE + t];
    mus[t] = s;   // raw column sums of z
  }
  __syncthreads();
  const float c1 = 0.01f / (float)(NB - 1);
  const float invN = 1.0f / (float)NB;
  float acc = 0.f;
  for (int k0 = 0; k0 < 256; k0 += 16) {
    int c = k0 + tx;
    {
      int r = i0 + ty;
      float base = 0.99f * rcov[(size_t)r * DE + c] +
                   c1 * (ZtZ[(size_t)r * DE + c] - mus[r] * mus[c] * invN);
      float e = -base;
      if (r == c) e += 1.0f - 1e-6f;
      Ea[ty][tx] = e;
    }
    {
      int r = j0 + ty;
      float base = 0.99f * rcov[(size_t)r * DE + c] +
                   c1 * (ZtZ[(size_t)r * DE + c] - mus[r] * mus[c] * invN);
      float e = -base;
      if (r == c) e += 1.0f - 1e-6f;
      Eb[ty][tx] = e;
    }
    __syncthreads();
#pragma unroll
    for (int k = 0; k < 16; ++k) acc += Ea[ty][k] * Eb[tx][k];   // E symmetric
    __syncthreads();
  }
  int r = i0 + ty, c = j0 + tx;
  float base = 0.99f * rcov[(size_t)r * DE + c] +
               c1 * (ZtZ[(size_t)r * DE + c] - mus[r] * mus[c] * invN);
  float e = -base;
  if (r == c) e += 1.0f - 1e-6f;
  X[(size_t)r * DE + c] = acc + e + ((r == c) ? 1.0f : 0.0f);
}

// dist: 4 rows per block, grid 512; rm = 0.99*rmean + 0.01*(sum mup)/N
__global__ __launch_bounds__(256) void dist_kernel(const float* __restrict__ z,
                                                   const float* __restrict__ rmean,
                                                   const float* __restrict__ mup,
                                                   const float* __restrict__ X,
                                                   float* __restrict__ dist) {
  __shared__ float cc[4][256];
  __shared__ float4 red[256];
  int n0 = blockIdx.x * 4, i = threadIdx.x;
  float s = 0.f;
  for (int b = 0; b < 64; ++b) s += mup[b * DE + i];
  float rmi = 0.99f * rmean[i] + 0.01f * s * (1.0f / (float)NB);
#pragma unroll
  for (int r = 0; r < 4; ++r) cc[r][i] = z[(size_t)(n0 + r) * DE + i] - rmi;
  __syncthreads();
  float y0 = 0.f, y1 = 0.f, y2 = 0.f, y3 = 0.f;
#pragma unroll 8
  for (int j = 0; j < DE; ++j) {
    float x = X[(size_t)j * DE + i];
    y0 += x * cc[0][j]; y1 += x * cc[1][j]; y2 += x * cc[2][j]; y3 += x * cc[3][j];
  }
  float4 v;
  v.x = y0 * cc[0][i]; v.y = y1 * cc[1][i]; v.z = y2 * cc[2][i]; v.w = y3 * cc[3][i];
  red[i] = v;
  __syncthreads();
  for (int sH = 128; sH > 0; sH >>= 1) {
    if (i < sH) {
      float4 a = red[i], b = red[i + sH];
      a.x += b.x; a.y += b.y; a.z += b.z; a.w += b.w;
      red[i] = a;
    }
    __syncthreads();
  }
  if (i < 4) {
    float4 tt = red[0];
    float d = (i == 0) ? tt.x : (i == 1) ? tt.y : (i == 2) ? tt.z : tt.w;
    dist[n0 + i] = sqrtf(fmaxf(d, 1e-8f));
  }
}

// ---------------- fused update: wave reductions, small-C wave sort, two-level extraction ----------------
__global__ __launch_bounds__(1024) void update_kernel(const float* __restrict__ dist,
                                                      const int* __restrict__ labels,
                                                      const float* __restrict__ weights,
                                                      const float* __restrict__ z,
                                                      float* __restrict__ memory) {
  __shared__ unsigned long long ikeys[NB];
  __shared__ unsigned long long ck[CAND_CAP];
  __shared__ unsigned long long gmin[16];
  __shared__ int slots[CAND_CAP], srcs[CAND_CAP];
  __shared__ float smin[16], smax[16];
  __shared__ int scnt[16];
  __shared__ float s_kl, s_dmin, s_inv;
  __shared__ int s_ccnt, s_m, s_stop, s_bg;
  int t = threadIdx.x;
  int wid = t >> 6, lane = t & 63;

  float mn = 1e30f, mx = -1e30f; int c1 = 0;
  for (int n = t; n < NB; n += 1024) {
    float d = dist[n];
    mn = fminf(mn, d); mx = fmaxf(mx, d);
    c1 += labels[n];
  }
#pragma unroll
  for (int o = 32; o > 0; o >>= 1) {
    mn = fminf(mn, __shfl_xor(mn, o, 64));
    mx = fmaxf(mx, __shfl_xor(mx, o, 64));
    c1 += __shfl_xor(c1, o, 64);
  }
  if (lane == 0) { smin[wid] = mn; smax[wid] = mx; scnt[wid] = c1; }
  if (t == 0) { s_ccnt = 0; s_m = 0; s_stop = 0; }
  __syncthreads();
  if (t == 0) {
    float a = 1e30f, b = -1e30f; int cc = 0;
    for (int i = 0; i < 16; ++i) { a = fminf(a, smin[i]); b = fmaxf(b, smax[i]); cc += scnt[i]; }
    float p1 = (float)cc / (float)NB;
    float p0 = (float)(NB - cc) / (float)NB;
    float kl = p0 * logf(fmaxf(2.f * p0, 1e-8f)) + p1 * logf(fmaxf(2.f * p1, 1e-8f));
    s_kl = fmaxf(kl, 0.f);
    s_dmin = a;
    s_inv = 1.0f / (b - a + 1e-8f);
  }
  __syncthreads();
  float kl = s_kl;

  for (int n = t; n < NB; n += 1024) {
    float imp = (1.0f + (dist[n] - s_dmin) * s_inv) * kl;
    ikeys[n] = ((unsigned long long)(unsigned)(~__float_as_uint(imp)) << 32) | (unsigned)n;
  }
  float thresh = 2.f * kl;
  for (int j = t; j < MEMN; j += 1024) {
    float wv = weights[j];
    if (wv < thresh) {
      int p = atomicAdd(&s_ccnt, 1);
      if (p < CAND_CAP) ck[p] = ((unsigned long long)__float_as_uint(wv) << 32) | (unsigned)j;
    }
  }
  __syncthreads();
  int C = s_ccnt; if (C > CAND_CAP) C = CAND_CAP;
  for (int i = t; i < CAND_CAP; i += 1024)
    if (i >= C) ck[i] = 0xFFFFFFFFFFFFFFFFULL;
  __syncthreads();
  if (C <= 64) {
    // single-wave rank sort, no barriers inside (wave 0 only)
    if (wid == 0) {
      unsigned long long key = (lane < C) ? ck[lane] : 0xFFFFFFFFFFFFFFFFULL;
      int rank = 0;
      for (int j = 0; j < 64; ++j) {
        unsigned long long o = (unsigned long long)__shfl((long long)key, j, 64);
        rank += (o < key) || (o == key && j < lane);
      }
      if (lane < C) ck[rank] = key;
    }
    __syncthreads();
  } else {
    bitonic_sort_u64(ck, CAND_CAP, t, 1024);
  }

  // group minima: wave wid owns ikeys[wid*128 .. wid*128+127]
  {
    unsigned long long a = ikeys[wid * 128 + lane];
    unsigned long long b = ikeys[wid * 128 + 64 + lane];
    unsigned long long mm = a < b ? a : b;
#pragma unroll
    for (int o = 32; o > 0; o >>= 1) {
      unsigned long long ot = (unsigned long long)__shfl_xor((long long)mm, o, 64);
      if (ot < mm) mm = ot;
    }
    if (lane == 0) gmin[wid] = mm;
  }
  __syncthreads();

  float prevv = 0.f;   // thread 0 only
  for (int i = 0; i < C; ++i) {
    if (t == 0) {
      unsigned long long best = 0xFFFFFFFFFFFFFFFFULL;
      for (int g = 0; g < 16; ++g) if (gmin[g] < best) best = gmin[g];
      float im = __uint_as_float(~(unsigned)(best >> 32));
      float wv = __uint_as_float((unsigned)(ck[i] >> 32));
      bool ok = (im > wv) && (i == 0 || prevv >= wv);
      if (ok) {
        int idx = (int)(best & 0xffffffffULL);
        slots[s_m] = (int)(ck[i] & 0xffffffffULL);
        srcs[s_m]  = idx;
        s_m++;
        prevv = im;
        ikeys[idx] = 0xFFFFFFFFFFFFFFFFULL;
        s_bg = idx >> 7;
      } else {
        s_stop = 1; s_bg = -1;
      }
    }
    __syncthreads();
    if (s_stop) break;
    if (wid == s_bg) {
      unsigned long long a = ikeys[wid * 128 + lane];
      unsigned long long b = ikeys[wid * 128 + 64 + lane];
      unsigned long long mm = a < b ? a : b;
#pragma unroll
      for (int o = 32; o > 0; o >>= 1) {
        unsigned long long ot = (unsigned long long)__shfl_xor((long long)mm, o, 64);
        if (ot < mm) mm = ot;
      }
      if (lane == 0) gmin[wid] = mm;
    }
    __syncthreads();
  }
  int m = s_m;
  for (int e = t; e < m * DE; e += 1024) {
    int i = e >> 8, d = e & 255;
    memory[(size_t)slots[i] * DE + d] = z[(size_t)srcs[i] * DE + d];
  }
}

// ---------------- fused Q/K/V projection GEMMs — A/B-reuse restructure ----------------
// Round-12: qkv was latency-bound (MfmaUtil 3.3%, VALUBusy 6.5%): K-part read all
// of `memory` 4x as A-gathers (once per 64-col tile); V-part staged each memory
// tile 2x. Restructure: K = 128 blocks, A loaded ONCE, loop 4 Wk B-tiles;
// V = 256 blocks, B staged ONCE, loop 2 Wv A-halves (Wv L2-resident).
// Q unchanged. Grid 1088 -> 448. Math bit-identical.
__global__ __launch_bounds__(256, 1) void qkv_kernel(
    const float* __restrict__ z, const float* __restrict__ memory,
    const float* __restrict__ Wq, const float* __restrict__ bq,
    const float* __restrict__ Wk, const float* __restrict__ bk,
    const float* __restrict__ Wv, const float* __restrict__ bv,
    unsigned short* __restrict__ Qbf, unsigned short* __restrict__ Kbf,
    unsigned short* __restrict__ Vtb) {
  __shared__ unsigned short Bsh[64 * 264];
  int flat = blockIdx.x;
  int tid = threadIdx.x;
  int w = tid >> 6, lane = tid & 63;
  int m = lane & 31, h = lane >> 5;

  if (flat < 64) {                 // ---- Q = z@Wq^T+bq (16x4 tiles) ----
    int gx = flat & 15, gy = flat >> 4;
    int arow = gx * 128 + w * 32 + m;
    int n0 = gy * 64;
    short8 af[16];
#pragma unroll
    for (int kc = 0; kc < 16; ++kc) {
      const float* src = &z[(size_t)arow * DE + kc * 16 + h * 8];
      af[kc] = pack8_bf16(*(const float4*)&src[0], *(const float4*)&src[4]);
    }
    {
      int r = tid >> 2, q = tid & 3;
      const float* src = &Wq[(size_t)(n0 + r) * DE + q * 64];
      unsigned short* dst = &Bsh[r * 264 + q * 64];
#pragma unroll
      for (int j = 0; j < 8; ++j)
        *(short8*)&dst[j * 8] = pack8_bf16(*(const float4*)&src[j * 8],
                                           *(const float4*)&src[j * 8 + 4]);
    }
    __syncthreads();
    float16 a0 = {}, a1 = {};
#pragma unroll
    for (int kc = 0; kc < 16; ++kc) {
      short8 b0 = *(const short8*)&Bsh[(0 * 32 + m) * 264 + kc * 16 + h * 8];
      short8 b1 = *(const short8*)&Bsh[(1 * 32 + m) * 264 + kc * 16 + h * 8];
      a0 = __builtin_amdgcn_mfma_f32_32x32x16_bf16(af[kc], b0, a0, 0, 0, 0);
      a1 = __builtin_amdgcn_mfma_f32_32x32x16_bf16(af[kc], b1, a1, 0, 0, 0);
    }
#pragma unroll
    for (int r = 0; r < 16; ++r) {
      int rr = (r & 3) + 8 * (r >> 2) + 4 * h;
      int orow = gx * 128 + w * 32 + rr;
      int oc0 = n0 + m, oc1 = n0 + 32 + m;
      Qbf[(size_t)orow * DE + oc0] = f2bf(a0[r] + bq[oc0]);
      Qbf[(size_t)orow * DE + oc1] = f2bf(a1[r] + bq[oc1]);
    }
  } else if (flat < 192) {         // ---- K = mem@Wk^T+bk: A once, loop 4 B-tiles ----
    int gx = flat - 64;            // 0..127
    int arow = gx * 128 + w * 32 + m;
    short8 af[16];
#pragma unroll
    for (int kc = 0; kc < 16; ++kc) {
      const float* src = &memory[(size_t)arow * DE + kc * 16 + h * 8];
      af[kc] = pack8_bf16(*(const float4*)&src[0], *(const float4*)&src[4]);
    }
    for (int g4 = 0; g4 < 4; ++g4) {
      int n0 = g4 * 64;
      __syncthreads();             // previous tile's reads complete
      {
        int r = tid >> 2, q = tid & 3;
        const float* src = &Wk[(size_t)(n0 + r) * DE + q * 64];
        unsigned short* dst = &Bsh[r * 264 + q * 64];
#pragma unroll
        for (int j = 0; j < 8; ++j)
          *(short8*)&dst[j * 8] = pack8_bf16(*(const float4*)&src[j * 8],
                                             *(const float4*)&src[j * 8 + 4]);
      }
      __syncthreads();
      float16 a0 = {}, a1 = {};
#pragma unroll
      for (int kc = 0; kc < 16; ++kc) {
        short8 b0 = *(const short8*)&Bsh[(0 * 32 + m) * 264 + kc * 16 + h * 8];
        short8 b1 = *(const short8*)&Bsh[(1 * 32 + m) * 264 + kc * 16 + h * 8];
        a0 = __builtin_amdgcn_mfma_f32_32x32x16_bf16(af[kc], b0, a0, 0, 0, 0);
        a1 = __builtin_amdgcn_mfma_f32_32x32x16_bf16(af[kc], b1, a1, 0, 0, 0);
      }
#pragma unroll
      for (int r = 0; r < 16; ++r) {
        int rr = (r & 3) + 8 * (r >> 2) + 4 * h;
        int orow = gx * 128 + w * 32 + rr;
        int oc0 = n0 + m, oc1 = n0 + 32 + m;
        Kbf[(size_t)orow * DE + oc0] = f2bf(a0[r] + bk[oc0]);
        Kbf[(size_t)orow * DE + oc1] = f2bf(a1[r] + bk[oc1]);
      }
    }
  } else {                         // ---- Vt = Wv@mem^T+bv: B once, loop 2 A-halves ----
    int gy = flat - 192;           // 0..255
    int n0 = gy * 64;
    {
      int r = tid >> 2, q = tid & 3;
      const float* src = &memory[(size_t)(n0 + r) * DE + q * 64];
      unsigned short* dst = &Bsh[r * 264 + q * 64];
#pragma unroll
      for (int j = 0; j < 8; ++j)
        *(short8*)&dst[j * 8] = pack8_bf16(*(const float4*)&src[j * 8],
                                           *(const float4*)&src[j * 8 + 4]);
    }
    __syncthreads();
    for (int gxv = 0; gxv < 2; ++gxv) {
      short8 af[16];
#pragma unroll
      for (int kc = 0; kc < 16; ++kc) {
        const float* src = &Wv[(size_t)(gxv * 128 + w * 32 + m) * DE + kc * 16 + h * 8];
        af[kc] = pack8_bf16(*(const float4*)&src[0], *(const float4*)&src[4]);
      }
      float16 a0 = {}, a1 = {};
#pragma unroll
      for (int kc = 0; kc < 16; ++kc) {
        short8 b0 = *(const short8*)&Bsh[(0 * 32 + m) * 264 + kc * 16 + h * 8];
        short8 b1 = *(const short8*)&Bsh[(1 * 32 + m) * 264 + kc * 16 + h * 8];
        a0 = __builtin_amdgcn_mfma_f32_32x32x16_bf16(af[kc], b0, a0, 0, 0, 0);
        a1 = __builtin_amdgcn_mfma_f32_32x32x16_bf16(af[kc], b1, a1, 0, 0, 0);
      }
#pragma unroll
      for (int r = 0; r < 16; ++r) {
        int rr = (r & 3) + 8 * (r >> 2) + 4 * h;
        int orow = gxv * 128 + w * 32 + rr;
        int oc0 = n0 + m, oc1 = n0 + 32 + m;
        Vtb[(size_t)(oc0 >> 5) * 8192 + (size_t)orow * 32 + (oc0 & 31)] = f2bf(a0[r] + bv[orow]);
        Vtb[(size_t)(oc1 >> 5) * 8192 + (size_t)orow * 32 + (oc1 & 31)] = f2bf(a1[r] + bv[orow]);
      }
    }
  }
}

// ---------------- MFMA flash attention: dh-merged, FSPL=32, T12 in-reg softmax ----------------
// Round-9 structure (best measured 46.3 us). 264-pad Ks layout retained
// (round-10 unpadded-XOR attempt regressed 5x on bank conflicts).
__global__ __launch_bounds__(512, 2) void flash_kernel(
    const unsigned short* __restrict__ Qb, const unsigned short* __restrict__ Kb,
    const unsigned short* __restrict__ Vtb, unsigned short* __restrict__ Opb,
    float* __restrict__ Lp) {
  __shared__ unsigned short Ks[32 * 264];
  __shared__ unsigned short Vs[256 * 40];

  int tid = threadIdx.x;
  int w = tid >> 6, lane = tid & 63;
  int m = lane & 31, h = lane >> 5;
  int sp = blockIdx.x, qg = blockIdx.y;
  int myrow = qg * 256 + w * 32 + m;

  short8 qf[16];
#pragma unroll
  for (int kc = 0; kc < 16; ++kc)
    qf[kc] = *(const short8*)&Qb[(size_t)myrow * DE + kc * 16 + h * 8];

  float16 O[8] = {};
  float lacc = 0.f;

  short8 kreg[2], vreg[2];
#define LOAD_TILES(kb_)                                                              \
  {                                                                                  \
    int kb = (kb_);                                                                  \
    _Pragma("unroll")                                                                \
    for (int i = 0; i < 2; ++i) {                                                    \
      int c = i * 512 + tid, kr = c >> 5, kcol = c & 31;                             \
      kreg[i] = *(const short8*)&Kb[(size_t)(kb + kr) * DE + kcol * 8];              \
    }                                                                                \
    const unsigned short* vg = &Vtb[(size_t)((kb) >> 5) * 8192];                     \
    _Pragma("unroll")                                                                \
    for (int i = 0; i < 2; ++i) {                                                    \
      int c = i * 512 + tid;                                                         \
      vreg[i] = *(const short8*)&vg[c * 8];                                          \
    }                                                                                \
  }
#define STORE_TILES()                                                                \
  {                                                                                  \
    _Pragma("unroll")                                                                \
    for (int i = 0; i < 2; ++i) {                                                    \
      int c = i * 512 + tid, kr = c >> 5, kcol = c & 31;                             \
      *(short8*)&Ks[kr * 264 + kcol * 8] = kreg[i];                                  \
    }                                                                                \
    _Pragma("unroll")                                                                \
    for (int i = 0; i < 2; ++i) {                                                    \
      int c = i * 512 + tid, dr = c >> 2, dc = c & 3;                                \
      *(short8*)&Vs[dr * 40 + dc * 8] = vreg[i];                                     \
    }                                                                                \
  }

  LOAD_TILES(sp * FKPS);

  for (int it = 0; it < FIT; ++it) {
    __syncthreads();               // LDS free (previous compute done)
    STORE_TILES();
    if (it + 1 < FIT) LOAD_TILES(sp * FKPS + (it + 1) * 32);
    __syncthreads();               // LDS ready

    // QK^T with SWAPPED operands: A=K-frag, B=Q-frag -> lane (m,h) holds
    // S[k=crow(r,h)][qrow=m]: the P-row of q-row m is lane-local.
    float16 s = {};
    __builtin_amdgcn_s_setprio(1);
#pragma unroll
    for (int kc = 0; kc < 16; ++kc) {
      short8 b0 = *(const short8*)&Ks[m * 264 + kc * 16 + h * 8];
      s = __builtin_amdgcn_mfma_f32_32x32x16_bf16(b0, qf[kc], s, 0, 0, 0);
    }
    __builtin_amdgcn_s_setprio(0);

    // p[r] = P[m][k=crow(r,h)]; exp(0.625*s - 11.0903549) == exp2(0.90168440*s - 16)
    float p[16];
#pragma unroll
    for (int r = 0; r < 16; ++r)
      p[r] = exp2f(fmaf(s[r], 0.90168440f, -16.0f));

    lacc += ((p[0] + p[1]) + (p[2] + p[3])) + ((p[4] + p[5]) + (p[6] + p[7])) +
            ((p[8] + p[9]) + (p[10] + p[11])) + ((p[12] + p[13]) + (p[14] + p[15]));

    unsigned c0 = cvtpk_bf16(p[0],  p[1]);
    unsigned c1 = cvtpk_bf16(p[2],  p[3]);
    unsigned c2 = cvtpk_bf16(p[4],  p[5]);
    unsigned c3 = cvtpk_bf16(p[6],  p[7]);
    unsigned c4 = cvtpk_bf16(p[8],  p[9]);
    unsigned c5 = cvtpk_bf16(p[10], p[11]);
    unsigned c6 = cvtpk_bf16(p[12], p[13]);
    unsigned c7 = cvtpk_bf16(p[14], p[15]);
    halfswap(c0, c2, h);
    halfswap(c1, c3, h);
    halfswap(c4, c6, h);
    halfswap(c5, c7, h);
    uint4v w0v = {c0, c1, c2, c3};
    uint4v w1v = {c4, c5, c6, c7};
    short8 pa0 = __builtin_bit_cast(short8, w0v);
    short8 pa1 = __builtin_bit_cast(short8, w1v);

    __builtin_amdgcn_s_setprio(1);
#pragma unroll
    for (int ct = 0; ct < 8; ++ct) {
      short8 vb0 = *(const short8*)&Vs[(ct * 32 + m) * 40 + h * 8];
      short8 vb1 = *(const short8*)&Vs[(ct * 32 + m) * 40 + 16 + h * 8];
      O[ct] = __builtin_amdgcn_mfma_f32_32x32x16_bf16(pa0, vb0, O[ct], 0, 0, 0);
      O[ct] = __builtin_amdgcn_mfma_f32_32x32x16_bf16(pa1, vb1, O[ct], 0, 0, 0);
    }
    __builtin_amdgcn_s_setprio(0);
  }
#undef LOAD_TILES
#undef STORE_TILES

  size_t ob = ((size_t)sp * NB + qg * 256 + w * 32) * DE;
#pragma unroll
  for (int ct = 0; ct < 8; ++ct)
#pragma unroll
    for (int r = 0; r < 16; ++r) {
      int rr = (r & 3) + 8 * (r >> 2) + 4 * h;
      Opb[ob + (size_t)rr * DE + ct * 32 + m] = f2bf(O[ct][r]);
    }
  float ltot = lacc + __shfl_xor(lacc, 32, 64);
  if (h == 0)
    Lp[sp * NB + qg * 256 + w * 32 + m] = ltot;
}

__global__ __launch_bounds__(256) void combine_kernel(const float* __restrict__ z,
                                                      const unsigned short* __restrict__ Opb,
                                                      const float* __restrict__ Lp,
                                                      float* __restrict__ out) {
  int n = blockIdx.x, c = threadIdx.x;
  float num = 0.f, den = 0.f;
#pragma unroll
  for (int s = 0; s < FSPL; ++s) {
    den += Lp[s * NB + n];
    num += bf2f(Opb[((size_t)s * NB + n) * DE + c]);
  }
  size_t base = (size_t)n * DE + c;
  out[base] = z[base] + 0.5f * num / den;
}

// ---------------- launcher: 8 launches, stream-ordered ----------------
extern "C" void kernel_launch(void* const* d_in, const int* in_sizes, int n_in,
                              void* d_out, int out_size, void* d_ws, size_t ws_size,
                              hipStream_t stream) {
  (void)in_sizes; (void)n_in; (void)out_size; (void)ws_size;
  const float* z       = (const float*)d_in[0];
  const int*   labels  = (const int*)d_in[1];
  float*       memory  = (float*)d_in[2];
  const float* weights = (const float*)d_in[3];
  const float* rmean   = (const float*)d_in[4];
  const float* rcov    = (const float*)d_in[5];
  const float* Wq      = (const float*)d_in[6];
  const float* bq      = (const float*)d_in[7];
  const float* Wk      = (const float*)d_in[8];
  const float* bk      = (const float*)d_in[9];
  const float* Wv      = (const float*)d_in[10];
  const float* bv      = (const float*)d_in[11];
  float* out = (float*)d_out;
  float* ws  = (float*)d_ws;

  unsigned short* Qbf = (unsigned short*)(ws + OFF_QB);
  unsigned short* Kbf = (unsigned short*)(ws + OFF_KB);
  unsigned short* Vtb = (unsigned short*)(ws + OFF_VTB);
  float* Lp           = ws + OFF_LP;
  unsigned short* Opb = (unsigned short*)(ws + OFF_OPB);
  float* SB    = ws + OFF_OPB;    // stats overlay (dead before flash writes Opb)
  float* A     = SB + SO_A;
  float* X     = SB + SO_X;
  float* mup   = SB + SO_MUP;
  float* dist  = SB + SO_DIST;

  mupart_kernel<<<64, 256, 0, stream>>>(z, mup, A);
  covpart_kernel<<<dim3(4, 4, 16), 256, 0, stream>>>(z, A);
  gemmx_kernel<<<dim3(16, 16), 256, 0, stream>>>(A, rcov, mup, X);
  dist_kernel<<<NB / 4, 256, 0, stream>>>(z, rmean, mup, X, dist);
  update_kernel<<<1, 1024, 0, stream>>>(dist, labels, weights, z, memory);
  qkv_kernel<<<448, 256, 0, stream>>>(z, memory, Wq, bq, Wk, bk, Wv, bv, Qbf, Kbf, Vtb);
  flash_kernel<<<dim3(FSPL, NB / 256), 512, 0, stream>>>(Qbf, Kbf, Vtb, Opb, Lp);
  combine_kernel<<<NB, 256, 0, stream>>>(z, Opb, Lp, out);
}

// Round 13
// 225.108 us; speedup vs baseline: 1.1401x; 1.0094x over previous
//
#include <hip/hip_runtime.h>
#include <math.h>

#define NB   2048
#define DE   256
#define MEMN 16384
#define CAND_CAP 256
#define FSPL 32
#define FKPS 512
#define FIT  16   // 16 iters x 32 K-rows

typedef __attribute__((ext_vector_type(8)))  short  short8;
typedef __attribute__((ext_vector_type(16))) float  float16;
typedef __attribute__((ext_vector_type(4)))  unsigned uint4v;
typedef __attribute__((ext_vector_type(2)))  unsigned uint2v;

// ---------------- workspace layout (float element offsets), ~51.6 MB (verified fit, round 3) ----------------
static const size_t OFF_QB   = 0;          // 2048*256 bf16
static const size_t OFF_KB   = 262144;     // 16384*256 bf16
static const size_t OFF_VTB  = 2359296;    // Vt tiled [512][256][32] bf16
static const size_t OFF_LP   = 4456448;    // 32*2048 floats
static const size_t OFF_OPB  = 4521984;    // 32*2048*256 bf16
// stats overlay (dead before flash writes Opb), relative to OFF_OPB:
static const size_t SO_A    = 0;
static const size_t SO_X    = 65536;
static const size_t SO_MUP  = 131072;
static const size_t SO_DIST = 147456;

__device__ inline unsigned short f2bf(float f) {
  unsigned u = __float_as_uint(f);
  unsigned r = (u + 0x7fffu + ((u >> 16) & 1u)) >> 16;
  return (unsigned short)r;
}
__device__ inline float bf2f(unsigned short s) {
  return __uint_as_float((unsigned)s << 16);
}

// pack two f32 -> one u32 of 2x bf16 (RNE, lo in [15:0]) — bit-identical to f2bf pairs
__device__ inline unsigned cvtpk_bf16(float lo, float hi) {
  unsigned r;
  asm("v_cvt_pk_bf16_f32 %0, %1, %2" : "=v"(r) : "v"(lo), "v"(hi));
  return r;
}
// pack 8 f32 (two float4) into a short8 of bf16 via 4 cvt_pk ops
__device__ inline short8 pack8_bf16(float4 f0, float4 f1) {
  uint4v u = {cvtpk_bf16(f0.x, f0.y), cvtpk_bf16(f0.z, f0.w),
              cvtpk_bf16(f1.x, f1.y), cvtpk_bf16(f1.z, f1.w)};
  return __builtin_bit_cast(short8, u);
}

// exchange lane-halves between a lower-k word and a higher-k word (T12).
__device__ inline void halfswap(unsigned& lo, unsigned& hi, int h) {
#if __has_builtin(__builtin_amdgcn_permlane32_swap)
  (void)h;
  uint2v r = __builtin_amdgcn_permlane32_swap(lo, hi, false, false);
  lo = r.x; hi = r.y;
#else
  unsigned a = (unsigned)__shfl_xor((int)lo, 32, 64);
  unsigned b = (unsigned)__shfl_xor((int)hi, 32, 64);
  unsigned nlo = (h == 0) ? lo : b;
  unsigned nhi = (h == 0) ? a  : hi;
  lo = nlo; hi = nhi;
#endif
}

__device__ inline void bitonic_sort_u64(unsigned long long* key, int n, int tid, int nth) {
  for (int k = 2; k <= n; k <<= 1) {
    for (int j = k >> 1; j > 0; j >>= 1) {
      __syncthreads();
      for (int i = tid; i < n; i += nth) {
        int ixj = i ^ j;
        if (ixj > i) {
          unsigned long long a = key[i], b = key[ixj];
          bool up = ((i & k) == 0);
          if ((a > b) == up) { key[i] = b; key[ixj] = a; }
        }
      }
    }
  }
  __syncthreads();
}

// ---------------- mean partials (also zeroes A for covpart's atomics) ----------------
__global__ __launch_bounds__(256) void mupart_kernel(const float* __restrict__ z,
                                                     float* __restrict__ mup,
                                                     float* __restrict__ Az) {
  int d = threadIdx.x;
  int r0 = blockIdx.x * 32;
  float4 zero4 = {0.f, 0.f, 0.f, 0.f};
  *(float4*)&Az[(size_t)blockIdx.x * 1024 + threadIdx.x * 4] = zero4;
  float s = 0.f;
  for (int r = 0; r < 32; ++r) s += z[(size_t)(r0 + r) * DE + d];
  mup[blockIdx.x * DE + d] = s;
}

// ---------------- raw second-moment partials: Z^T Z over 128-row slice, atomicAdd into A ----------------
__global__ __launch_bounds__(256) void covpart_kernel(const float* __restrict__ z,
                                                      float* __restrict__ A) {
  __shared__ float As[16][68];
  __shared__ float Bs[16][68];
  int tid = threadIdx.x, tx = tid & 15, ty = tid >> 4;
  int i0 = blockIdx.x * 64, j0 = blockIdx.y * 64;
  int nbase = blockIdx.z * 128;
  float acc[4][4] = {};
  for (int nt = 0; nt < 8; ++nt) {
    int n0 = nbase + nt * 16;
    for (int e = tid; e < 1024; e += 256) {
      int c = e & 63, nn = e >> 6;
      As[nn][c] = z[(size_t)(n0 + nn) * DE + i0 + c];
      Bs[nn][c] = z[(size_t)(n0 + nn) * DE + j0 + c];
    }
    __syncthreads();
#pragma unroll
    for (int nn = 0; nn < 16; ++nn) {
      float4 a4 = *(const float4*)&As[nn][ty * 4];
      float4 b4 = *(const float4*)&Bs[nn][tx * 4];
      acc[0][0] += a4.x*b4.x; acc[0][1] += a4.x*b4.y; acc[0][2] += a4.x*b4.z; acc[0][3] += a4.x*b4.w;
      acc[1][0] += a4.y*b4.x; acc[1][1] += a4.y*b4.y; acc[1][2] += a4.y*b4.z; acc[1][3] += a4.y*b4.w;
      acc[2][0] += a4.z*b4.x; acc[2][1] += a4.z*b4.y; acc[2][2] += a4.z*b4.z; acc[2][3] += a4.z*b4.w;
      acc[3][0] += a4.w*b4.x; acc[3][1] += a4.w*b4.y; acc[3][2] += a4.w*b4.z; acc[3][3] += a4.w*b4.w;
    }
    __syncthreads();
  }
  for (int r = 0; r < 4; ++r) {
    int i = i0 + ty * 4 + r;
    for (int c = 0; c < 4; ++c) {
      int j = j0 + tx * 4 + c;
      atomicAdd(&A[(size_t)i * DE + j], acc[r][c]);
    }
  }
}

// ---------------- X = I + E + E^2 (E = I - A), E built on-the-fly ----------------
__global__ __launch_bounds__(256) void gemmx_kernel(const float* __restrict__ ZtZ,
                                                    const float* __restrict__ rcov,
                                                    const float* __restrict__ mup,
                                                    float* __restrict__ X) {
  __shared__ float Ea[16][17];
  __shared__ float Eb[16][17];
  __shared__ float mus[256];
  int t = threadIdx.x, tx = t & 15, ty = t >> 4;
  int i0 = blockIdx.x * 16, j0 = blockIdx.y * 16;
  {
    float s = 0.f;
    for (int b = 0; b < 64; ++b) s += mup[b * DE + t];
    mus[t] = s;   // raw column sums of z
  }
  __syncthreads();
  const float c1 = 0.01f / (float)(NB - 1);
  const float invN = 1.0f / (float)NB;
  float acc = 0.f;
  for (int k0 = 0; k0 < 256; k0 += 16) {
    int c = k0 + tx;
    {
      int r = i0 + ty;
      float base = 0.99f * rcov[(size_t)r * DE + c] +
                   c1 * (ZtZ[(size_t)r * DE + c] - mus[r] * mus[c] * invN);
      float e = -base;
      if (r == c) e += 1.0f - 1e-6f;
      Ea[ty][tx] = e;
    }
    {
      int r = j0 + ty;
      float base = 0.99f * rcov[(size_t)r * DE + c] +
                   c1 * (ZtZ[(size_t)r * DE + c] - mus[r] * mus[c] * invN);
      float e = -base;
      if (r == c) e += 1.0f - 1e-6f;
      Eb[ty][tx] = e;
    }
    __syncthreads();
#pragma unroll
    for (int k = 0; k < 16; ++k) acc += Ea[ty][k] * Eb[tx][k];   // E symmetric
    __syncthreads();
  }
  int r = i0 + ty, c = j0 + tx;
  float base = 0.99f * rcov[(size_t)r * DE + c] +
               c1 * (ZtZ[(size_t)r * DE + c] - mus[r] * mus[c] * invN);
  float e = -base;
  if (r == c) e += 1.0f - 1e-6f;
  X[(size_t)r * DE + c] = acc + e + ((r == c) ? 1.0f : 0.0f);
}

// dist: 8 rows per block, grid 256 — halves per-block X re-reads (134->67 MB L2)
__global__ __launch_bounds__(256) void dist_kernel(const float* __restrict__ z,
                                                   const float* __restrict__ rmean,
                                                   const float* __restrict__ mup,
                                                   const float* __restrict__ X,
                                                   float* __restrict__ dist) {
  __shared__ float cc[8][256];
  __shared__ float4 red[256];
  int n0 = blockIdx.x * 8, i = threadIdx.x;
  float s = 0.f;
  for (int b = 0; b < 64; ++b) s += mup[b * DE + i];
  float rmi = 0.99f * rmean[i] + 0.01f * s * (1.0f / (float)NB);
#pragma unroll
  for (int r = 0; r < 8; ++r) cc[r][i] = z[(size_t)(n0 + r) * DE + i] - rmi;
  __syncthreads();
  float y[8] = {};
#pragma unroll 8
  for (int j = 0; j < DE; ++j) {
    float x = X[(size_t)j * DE + i];
#pragma unroll
    for (int r = 0; r < 8; ++r) y[r] += x * cc[r][j];
  }
  // rows 0..3
  {
    float4 v;
    v.x = y[0] * cc[0][i]; v.y = y[1] * cc[1][i]; v.z = y[2] * cc[2][i]; v.w = y[3] * cc[3][i];
    red[i] = v;
    __syncthreads();
    for (int sH = 128; sH > 0; sH >>= 1) {
      if (i < sH) {
        float4 a = red[i], b = red[i + sH];
        a.x += b.x; a.y += b.y; a.z += b.z; a.w += b.w;
        red[i] = a;
      }
      __syncthreads();
    }
    if (i < 4) {
      float4 tt = red[0];
      float d = (i == 0) ? tt.x : (i == 1) ? tt.y : (i == 2) ? tt.z : tt.w;
      dist[n0 + i] = sqrtf(fmaxf(d, 1e-8f));
    }
    __syncthreads();
  }
  // rows 4..7
  {
    float4 v;
    v.x = y[4] * cc[4][i]; v.y = y[5] * cc[5][i]; v.z = y[6] * cc[6][i]; v.w = y[7] * cc[7][i];
    red[i] = v;
    __syncthreads();
    for (int sH = 128; sH > 0; sH >>= 1) {
      if (i < sH) {
        float4 a = red[i], b = red[i + sH];
        a.x += b.x; a.y += b.y; a.z += b.z; a.w += b.w;
        red[i] = a;
      }
      __syncthreads();
    }
    if (i < 4) {
      float4 tt = red[0];
      float d = (i == 0) ? tt.x : (i == 1) ? tt.y : (i == 2) ? tt.z : tt.w;
      dist[n0 + 4 + i] = sqrtf(fmaxf(d, 1e-8f));
    }
  }
}

// ---------------- fused update: wave reductions, small-C wave sort, two-level extraction ----------------
__global__ __launch_bounds__(1024) void update_kernel(const float* __restrict__ dist,
                                                      const int* __restrict__ labels,
                                                      const float* __restrict__ weights,
                                                      const float* __restrict__ z,
                                                      float* __restrict__ memory) {
  __shared__ unsigned long long ikeys[NB];
  __shared__ unsigned long long ck[CAND_CAP];
  __shared__ unsigned long long gmin[16];
  __shared__ int slots[CAND_CAP], srcs[CAND_CAP];
  __shared__ float smin[16], smax[16];
  __shared__ int scnt[16];
  __shared__ float s_kl, s_dmin, s_inv;
  __shared__ int s_ccnt, s_m, s_stop, s_bg;
  int t = threadIdx.x;
  int wid = t >> 6, lane = t & 63;

  float mn = 1e30f, mx = -1e30f; int c1 = 0;
  for (int n = t; n < NB; n += 1024) {
    float d = dist[n];
    mn = fminf(mn, d); mx = fmaxf(mx, d);
    c1 += labels[n];
  }
#pragma unroll
  for (int o = 32; o > 0; o >>= 1) {
    mn = fminf(mn, __shfl_xor(mn, o, 64));
    mx = fmaxf(mx, __shfl_xor(mx, o, 64));
    c1 += __shfl_xor(c1, o, 64);
  }
  if (lane == 0) { smin[wid] = mn; smax[wid] = mx; scnt[wid] = c1; }
  if (t == 0) { s_ccnt = 0; s_m = 0; s_stop = 0; }
  __syncthreads();
  if (t == 0) {
    float a = 1e30f, b = -1e30f; int cc = 0;
    for (int i = 0; i < 16; ++i) { a = fminf(a, smin[i]); b = fmaxf(b, smax[i]); cc += scnt[i]; }
    float p1 = (float)cc / (float)NB;
    float p0 = (float)(NB - cc) / (float)NB;
    float kl = p0 * logf(fmaxf(2.f * p0, 1e-8f)) + p1 * logf(fmaxf(2.f * p1, 1e-8f));
    s_kl = fmaxf(kl, 0.f);
    s_dmin = a;
    s_inv = 1.0f / (b - a + 1e-8f);
  }
  __syncthreads();
  float kl = s_kl;

  for (int n = t; n < NB; n += 1024) {
    float imp = (1.0f + (dist[n] - s_dmin) * s_inv) * kl;
    ikeys[n] = ((unsigned long long)(unsigned)(~__float_as_uint(imp)) << 32) | (unsigned)n;
  }
  float thresh = 2.f * kl;
  for (int j = t; j < MEMN; j += 1024) {
    float wv = weights[j];
    if (wv < thresh) {
      int p = atomicAdd(&s_ccnt, 1);
      if (p < CAND_CAP) ck[p] = ((unsigned long long)__float_as_uint(wv) << 32) | (unsigned)j;
    }
  }
  __syncthreads();
  int C = s_ccnt; if (C > CAND_CAP) C = CAND_CAP;
  for (int i = t; i < CAND_CAP; i += 1024)
    if (i >= C) ck[i] = 0xFFFFFFFFFFFFFFFFULL;
  __syncthreads();
  if (C <= 64) {
    // single-wave rank sort, no barriers inside (wave 0 only)
    if (wid == 0) {
      unsigned long long key = (lane < C) ? ck[lane] : 0xFFFFFFFFFFFFFFFFULL;
      int rank = 0;
      for (int j = 0; j < 64; ++j) {
        unsigned long long o = (unsigned long long)__shfl((long long)key, j, 64);
        rank += (o < key) || (o == key && j < lane);
      }
      if (lane < C) ck[rank] = key;
    }
    __syncthreads();
  } else {
    bitonic_sort_u64(ck, CAND_CAP, t, 1024);
  }

  // group minima: wave wid owns ikeys[wid*128 .. wid*128+127]
  {
    unsigned long long a = ikeys[wid * 128 + lane];
    unsigned long long b = ikeys[wid * 128 + 64 + lane];
    unsigned long long mm = a < b ? a : b;
#pragma unroll
    for (int o = 32; o > 0; o >>= 1) {
      unsigned long long ot = (unsigned long long)__shfl_xor((long long)mm, o, 64);
      if (ot < mm) mm = ot;
    }
    if (lane == 0) gmin[wid] = mm;
  }
  __syncthreads();

  float prevv = 0.f;   // thread 0 only
  for (int i = 0; i < C; ++i) {
    if (t == 0) {
      unsigned long long best = 0xFFFFFFFFFFFFFFFFULL;
      for (int g = 0; g < 16; ++g) if (gmin[g] < best) best = gmin[g];
      float im = __uint_as_float(~(unsigned)(best >> 32));
      float wv = __uint_as_float((unsigned)(ck[i] >> 32));
      bool ok = (im > wv) && (i == 0 || prevv >= wv);
      if (ok) {
        int idx = (int)(best & 0xffffffffULL);
        slots[s_m] = (int)(ck[i] & 0xffffffffULL);
        srcs[s_m]  = idx;
        s_m++;
        prevv = im;
        ikeys[idx] = 0xFFFFFFFFFFFFFFFFULL;
        s_bg = idx >> 7;
      } else {
        s_stop = 1; s_bg = -1;
      }
    }
    __syncthreads();
    if (s_stop) break;
    if (wid == s_bg) {
      unsigned long long a = ikeys[wid * 128 + lane];
      unsigned long long b = ikeys[wid * 128 + 64 + lane];
      unsigned long long mm = a < b ? a : b;
#pragma unroll
      for (int o = 32; o > 0; o >>= 1) {
        unsigned long long ot = (unsigned long long)__shfl_xor((long long)mm, o, 64);
        if (ot < mm) mm = ot;
      }
      if (lane == 0) gmin[wid] = mm;
    }
    __syncthreads();
  }
  int m = s_m;
  for (int e = t; e < m * DE; e += 1024) {
    int i = e >> 8, d = e & 255;
    memory[(size_t)slots[i] * DE + d] = z[(size_t)srcs[i] * DE + d];
  }
}

// ---------------- fused Q/K/V projection GEMMs — A/B-reuse structure (round-12, verified) ----------------
__global__ __launch_bounds__(256, 1) void qkv_kernel(
    const float* __restrict__ z, const float* __restrict__ memory,
    const float* __restrict__ Wq, const float* __restrict__ bq,
    const float* __restrict__ Wk, const float* __restrict__ bk,
    const float* __restrict__ Wv, const float* __restrict__ bv,
    unsigned short* __restrict__ Qbf, unsigned short* __restrict__ Kbf,
    unsigned short* __restrict__ Vtb) {
  __shared__ unsigned short Bsh[64 * 264];
  int flat = blockIdx.x;
  int tid = threadIdx.x;
  int w = tid >> 6, lane = tid & 63;
  int m = lane & 31, h = lane >> 5;

  if (flat < 64) {                 // ---- Q = z@Wq^T+bq (16x4 tiles) ----
    int gx = flat & 15, gy = flat >> 4;
    int arow = gx * 128 + w * 32 + m;
    int n0 = gy * 64;
    short8 af[16];
#pragma unroll
    for (int kc = 0; kc < 16; ++kc) {
      const float* src = &z[(size_t)arow * DE + kc * 16 + h * 8];
      af[kc] = pack8_bf16(*(const float4*)&src[0], *(const float4*)&src[4]);
    }
    {
      int r = tid >> 2, q = tid & 3;
      const float* src = &Wq[(size_t)(n0 + r) * DE + q * 64];
      unsigned short* dst = &Bsh[r * 264 + q * 64];
#pragma unroll
      for (int j = 0; j < 8; ++j)
        *(short8*)&dst[j * 8] = pack8_bf16(*(const float4*)&src[j * 8],
                                           *(const float4*)&src[j * 8 + 4]);
    }
    __syncthreads();
    float16 a0 = {}, a1 = {};
#pragma unroll
    for (int kc = 0; kc < 16; ++kc) {
      short8 b0 = *(const short8*)&Bsh[(0 * 32 + m) * 264 + kc * 16 + h * 8];
      short8 b1 = *(const short8*)&Bsh[(1 * 32 + m) * 264 + kc * 16 + h * 8];
      a0 = __builtin_amdgcn_mfma_f32_32x32x16_bf16(af[kc], b0, a0, 0, 0, 0);
      a1 = __builtin_amdgcn_mfma_f32_32x32x16_bf16(af[kc], b1, a1, 0, 0, 0);
    }
#pragma unroll
    for (int r = 0; r < 16; ++r) {
      int rr = (r & 3) + 8 * (r >> 2) + 4 * h;
      int orow = gx * 128 + w * 32 + rr;
      int oc0 = n0 + m, oc1 = n0 + 32 + m;
      Qbf[(size_t)orow * DE + oc0] = f2bf(a0[r] + bq[oc0]);
      Qbf[(size_t)orow * DE + oc1] = f2bf(a1[r] + bq[oc1]);
    }
  } else if (flat < 192) {         // ---- K = mem@Wk^T+bk: A once, loop 4 B-tiles ----
    int gx = flat - 64;            // 0..127
    int arow = gx * 128 + w * 32 + m;
    short8 af[16];
#pragma unroll
    for (int kc = 0; kc < 16; ++kc) {
      const float* src = &memory[(size_t)arow * DE + kc * 16 + h * 8];
      af[kc] = pack8_bf16(*(const float4*)&src[0], *(const float4*)&src[4]);
    }
    for (int g4 = 0; g4 < 4; ++g4) {
      int n0 = g4 * 64;
      __syncthreads();             // previous tile's reads complete
      {
        int r = tid >> 2, q = tid & 3;
        const float* src = &Wk[(size_t)(n0 + r) * DE + q * 64];
        unsigned short* dst = &Bsh[r * 264 + q * 64];
#pragma unroll
        for (int j = 0; j < 8; ++j)
          *(short8*)&dst[j * 8] = pack8_bf16(*(const float4*)&src[j * 8],
                                             *(const float4*)&src[j * 8 + 4]);
      }
      __syncthreads();
      float16 a0 = {}, a1 = {};
#pragma unroll
      for (int kc = 0; kc < 16; ++kc) {
        short8 b0 = *(const short8*)&Bsh[(0 * 32 + m) * 264 + kc * 16 + h * 8];
        short8 b1 = *(const short8*)&Bsh[(1 * 32 + m) * 264 + kc * 16 + h * 8];
        a0 = __builtin_amdgcn_mfma_f32_32x32x16_bf16(af[kc], b0, a0, 0, 0, 0);
        a1 = __builtin_amdgcn_mfma_f32_32x32x16_bf16(af[kc], b1, a1, 0, 0, 0);
      }
#pragma unroll
      for (int r = 0; r < 16; ++r) {
        int rr = (r & 3) + 8 * (r >> 2) + 4 * h;
        int orow = gx * 128 + w * 32 + rr;
        int oc0 = n0 + m, oc1 = n0 + 32 + m;
        Kbf[(size_t)orow * DE + oc0] = f2bf(a0[r] + bk[oc0]);
        Kbf[(size_t)orow * DE + oc1] = f2bf(a1[r] + bk[oc1]);
      }
    }
  } else {                         // ---- Vt = Wv@mem^T+bv: B once, loop 2 A-halves ----
    int gy = flat - 192;           // 0..255
    int n0 = gy * 64;
    {
      int r = tid >> 2, q = tid & 3;
      const float* src = &memory[(size_t)(n0 + r) * DE + q * 64];
      unsigned short* dst = &Bsh[r * 264 + q * 64];
#pragma unroll
      for (int j = 0; j < 8; ++j)
        *(short8*)&dst[j * 8] = pack8_bf16(*(const float4*)&src[j * 8],
                                           *(const float4*)&src[j * 8 + 4]);
    }
    __syncthreads();
    for (int gxv = 0; gxv < 2; ++gxv) {
      short8 af[16];
#pragma unroll
      for (int kc = 0; kc < 16; ++kc) {
        const float* src = &Wv[(size_t)(gxv * 128 + w * 32 + m) * DE + kc * 16 + h * 8];
        af[kc] = pack8_bf16(*(const float4*)&src[0], *(const float4*)&src[4]);
      }
      float16 a0 = {}, a1 = {};
#pragma unroll
      for (int kc = 0; kc < 16; ++kc) {
        short8 b0 = *(const short8*)&Bsh[(0 * 32 + m) * 264 + kc * 16 + h * 8];
        short8 b1 = *(const short8*)&Bsh[(1 * 32 + m) * 264 + kc * 16 + h * 8];
        a0 = __builtin_amdgcn_mfma_f32_32x32x16_bf16(af[kc], b0, a0, 0, 0, 0);
        a1 = __builtin_amdgcn_mfma_f32_32x32x16_bf16(af[kc], b1, a1, 0, 0, 0);
      }
#pragma unroll
      for (int r = 0; r < 16; ++r) {
        int rr = (r & 3) + 8 * (r >> 2) + 4 * h;
        int orow = gxv * 128 + w * 32 + rr;
        int oc0 = n0 + m, oc1 = n0 + 32 + m;
        Vtb[(size_t)(oc0 >> 5) * 8192 + (size_t)orow * 32 + (oc0 & 31)] = f2bf(a0[r] + bv[orow]);
        Vtb[(size_t)(oc1 >> 5) * 8192 + (size_t)orow * 32 + (oc1 & 31)] = f2bf(a1[r] + bv[orow]);
      }
    }
  }
}

// ---------------- MFMA flash attention: dh-merged, FSPL=32, T12 in-reg softmax ----------------
// Round-9 structure (best measured). 264-pad Ks layout retained.
__global__ __launch_bounds__(512, 2) void flash_kernel(
    const unsigned short* __restrict__ Qb, const unsigned short* __restrict__ Kb,
    const unsigned short* __restrict__ Vtb, unsigned short* __restrict__ Opb,
    float* __restrict__ Lp) {
  __shared__ unsigned short Ks[32 * 264];
  __shared__ unsigned short Vs[256 * 40];

  int tid = threadIdx.x;
  int w = tid >> 6, lane = tid & 63;
  int m = lane & 31, h = lane >> 5;
  int sp = blockIdx.x, qg = blockIdx.y;
  int myrow = qg * 256 + w * 32 + m;

  short8 qf[16];
#pragma unroll
  for (int kc = 0; kc < 16; ++kc)
    qf[kc] = *(const short8*)&Qb[(size_t)myrow * DE + kc * 16 + h * 8];

  float16 O[8] = {};
  float lacc = 0.f;

  short8 kreg[2], vreg[2];
#define LOAD_TILES(kb_)                                                              \
  {                                                                                  \
    int kb = (kb_);                                                                  \
    _Pragma("unroll")                                                                \
    for (int i = 0; i < 2; ++i) {                                                    \
      int c = i * 512 + tid, kr = c >> 5, kcol = c & 31;                             \
      kreg[i] = *(const short8*)&Kb[(size_t)(kb + kr) * DE + kcol * 8];              \
    }                                                                                \
    const unsigned short* vg = &Vtb[(size_t)((kb) >> 5) * 8192];                     \
    _Pragma("unroll")                                                                \
    for (int i = 0; i < 2; ++i) {                                                    \
      int c = i * 512 + tid;                                                         \
      vreg[i] = *(const short8*)&vg[c * 8];                                          \
    }                                                                                \
  }
#define STORE_TILES()                                                                \
  {                                                                                  \
    _Pragma("unroll")                                                                \
    for (int i = 0; i < 2; ++i) {                                                    \
      int c = i * 512 + tid, kr = c >> 5, kcol = c & 31;                             \
      *(short8*)&Ks[kr * 264 + kcol * 8] = kreg[i];                                  \
    }                                                                                \
    _Pragma("unroll")                                                                \
    for (int i = 0; i < 2; ++i) {                                                    \
      int c = i * 512 + tid, dr = c >> 2, dc = c & 3;                                \
      *(short8*)&Vs[dr * 40 + dc * 8] = vreg[i];                                     \
    }                                                                                \
  }

  LOAD_TILES(sp * FKPS);

  for (int it = 0; it < FIT; ++it) {
    __syncthreads();               // LDS free (previous compute done)
    STORE_TILES();
    if (it + 1 < FIT) LOAD_TILES(sp * FKPS + (it + 1) * 32);
    __syncthreads();               // LDS ready

    // QK^T with SWAPPED operands: A=K-frag, B=Q-frag -> lane (m,h) holds
    // S[k=crow(r,h)][qrow=m]: the P-row of q-row m is lane-local.
    float16 s = {};
    __builtin_amdgcn_s_setprio(1);
#pragma unroll
    for (int kc = 0; kc < 16; ++kc) {
      short8 b0 = *(const short8*)&Ks[m * 264 + kc * 16 + h * 8];
      s = __builtin_amdgcn_mfma_f32_32x32x16_bf16(b0, qf[kc], s, 0, 0, 0);
    }
    __builtin_amdgcn_s_setprio(0);

    // p[r] = P[m][k=crow(r,h)]; exp(0.625*s - 11.0903549) == exp2(0.90168440*s - 16)
    float p[16];
#pragma unroll
    for (int r = 0; r < 16; ++r)
      p[r] = exp2f(fmaf(s[r], 0.90168440f, -16.0f));

    lacc += ((p[0] + p[1]) + (p[2] + p[3])) + ((p[4] + p[5]) + (p[6] + p[7])) +
            ((p[8] + p[9]) + (p[10] + p[11])) + ((p[12] + p[13]) + (p[14] + p[15]));

    unsigned c0 = cvtpk_bf16(p[0],  p[1]);
    unsigned c1 = cvtpk_bf16(p[2],  p[3]);
    unsigned c2 = cvtpk_bf16(p[4],  p[5]);
    unsigned c3 = cvtpk_bf16(p[6],  p[7]);
    unsigned c4 = cvtpk_bf16(p[8],  p[9]);
    unsigned c5 = cvtpk_bf16(p[10], p[11]);
    unsigned c6 = cvtpk_bf16(p[12], p[13]);
    unsigned c7 = cvtpk_bf16(p[14], p[15]);
    halfswap(c0, c2, h);
    halfswap(c1, c3, h);
    halfswap(c4, c6, h);
    halfswap(c5, c7, h);
    uint4v w0v = {c0, c1, c2, c3};
    uint4v w1v = {c4, c5, c6, c7};
    short8 pa0 = __builtin_bit_cast(short8, w0v);
    short8 pa1 = __builtin_bit_cast(short8, w1v);

    __builtin_amdgcn_s_setprio(1);
#pragma unroll
    for (int ct = 0; ct < 8; ++ct) {
      short8 vb0 = *(const short8*)&Vs[(ct * 32 + m) * 40 + h * 8];
      short8 vb1 = *(const short8*)&Vs[(ct * 32 + m) * 40 + 16 + h * 8];
      O[ct] = __builtin_amdgcn_mfma_f32_32x32x16_bf16(pa0, vb0, O[ct], 0, 0, 0);
      O[ct] = __builtin_amdgcn_mfma_f32_32x32x16_bf16(pa1, vb1, O[ct], 0, 0, 0);
    }
    __builtin_amdgcn_s_setprio(0);
  }
#undef LOAD_TILES
#undef STORE_TILES

  size_t ob = ((size_t)sp * NB + qg * 256 + w * 32) * DE;
#pragma unroll
  for (int ct = 0; ct < 8; ++ct)
#pragma unroll
    for (int r = 0; r < 16; ++r) {
      int rr = (r & 3) + 8 * (r >> 2) + 4 * h;
      Opb[ob + (size_t)rr * DE + ct * 32 + m] = f2bf(O[ct][r]);
    }
  float ltot = lacc + __shfl_xor(lacc, 32, 64);
  if (h == 0)
    Lp[sp * NB + qg * 256 + w * 32 + m] = ltot;
}

// combine: vectorized short8 Opb reads (16 B/lane), 8 rows/block, grid 256.
// Per-channel arithmetic identical to scalar version (same s-order, 0.5f*num/den).
__global__ __launch_bounds__(256) void combine_kernel(const float* __restrict__ z,
                                                      const unsigned short* __restrict__ Opb,
                                                      const float* __restrict__ Lp,
                                                      float* __restrict__ out) {
  int t = threadIdx.x;
  int n = blockIdx.x * 8 + (t >> 5);
  int c0 = (t & 31) * 8;
  float num[8] = {};
  float den = 0.f;
#pragma unroll
  for (int s = 0; s < FSPL; ++s) {
    den += Lp[s * NB + n];
    short8 v = *(const short8*)&Opb[((size_t)s * NB + n) * DE + c0];
#pragma unroll
    for (int j = 0; j < 8; ++j) num[j] += bf2f((unsigned short)v[j]);
  }
  size_t base = (size_t)n * DE + c0;
  float4 o0, o1;
  o0.x = z[base + 0] + 0.5f * num[0] / den;
  o0.y = z[base + 1] + 0.5f * num[1] / den;
  o0.z = z[base + 2] + 0.5f * num[2] / den;
  o0.w = z[base + 3] + 0.5f * num[3] / den;
  o1.x = z[base + 4] + 0.5f * num[4] / den;
  o1.y = z[base + 5] + 0.5f * num[5] / den;
  o1.z = z[base + 6] + 0.5f * num[6] / den;
  o1.w = z[base + 7] + 0.5f * num[7] / den;
  *(float4*)&out[base] = o0;
  *(float4*)&out[base + 4] = o1;
}

// ---------------- launcher: 8 launches, stream-ordered ----------------
extern "C" void kernel_launch(void* const* d_in, const int* in_sizes, int n_in,
                              void* d_out, int out_size, void* d_ws, size_t ws_size,
                              hipStream_t stream) {
  (void)in_sizes; (void)n_in; (void)out_size; (void)ws_size;
  const float* z       = (const float*)d_in[0];
  const int*   labels  = (const int*)d_in[1];
  float*       memory  = (float*)d_in[2];
  const float* weights = (const float*)d_in[3];
  const float* rmean   = (const float*)d_in[4];
  const float* rcov    = (const float*)d_in[5];
  const float* Wq      = (const float*)d_in[6];
  const float* bq      = (const float*)d_in[7];
  const float* Wk      = (const float*)d_in[8];
  const float* bk      = (const float*)d_in[9];
  const float* Wv      = (const float*)d_in[10];
  const float* bv      = (const float*)d_in[11];
  float* out = (float*)d_out;
  float* ws  = (float*)d_ws;

  unsigned short* Qbf = (unsigned short*)(ws + OFF_QB);
  unsigned short* Kbf = (unsigned short*)(ws + OFF_KB);
  unsigned short* Vtb = (unsigned short*)(ws + OFF_VTB);
  float* Lp           = ws + OFF_LP;
  unsigned short* Opb = (unsigned short*)(ws + OFF_OPB);
  float* SB    = ws + OFF_OPB;    // stats overlay (dead before flash writes Opb)
  float* A     = SB + SO_A;
  float* X     = SB + SO_X;
  float* mup   = SB + SO_MUP;
  float* dist  = SB + SO_DIST;

  mupart_kernel<<<64, 256, 0, stream>>>(z, mup, A);
  covpart_kernel<<<dim3(4, 4, 16), 256, 0, stream>>>(z, A);
  gemmx_kernel<<<dim3(16, 16), 256, 0, stream>>>(A, rcov, mup, X);
  dist_kernel<<<NB / 8, 256, 0, stream>>>(z, rmean, mup, X, dist);
  update_kernel<<<1, 1024, 0, stream>>>(dist, labels, weights, z, memory);
  qkv_kernel<<<448, 256, 0, stream>>>(z, memory, Wq, bq, Wk, bk, Wv, bv, Qbf, Kbf, Vtb);
  flash_kernel<<<dim3(FSPL, NB / 256), 512, 0, stream>>>(Qbf, Kbf, Vtb, Opb, Lp);
  combine_kernel<<<NB / 8, 256, 0, stream>>>(z, Opb, Lp, out);
}